// Round 5
// baseline (1084.702 us; speedup 1.0000x reference)
//
#include <hip/hip_runtime.h>
#include <stdint.h>

#define N_NODES 32768
#define N_EDGES 524288
#define NODE_MASK (N_NODES - 1)

// ---------------- threefry2x32 (Threefry-20, verified vs spec) --------------
__device__ __forceinline__ uint32_t rotl32(uint32_t v, int r) {
  return (v << r) | (v >> (32 - r));
}

__device__ __forceinline__ void threefry2x32(uint32_t k0, uint32_t k1,
                                             uint32_t x0, uint32_t x1,
                                             uint32_t* o0, uint32_t* o1) {
  uint32_t k2 = k0 ^ k1 ^ 0x1BD11BDAu;
  x0 += k0; x1 += k1;
  x0 += x1; x1 = rotl32(x1, 13); x1 ^= x0;
  x0 += x1; x1 = rotl32(x1, 15); x1 ^= x0;
  x0 += x1; x1 = rotl32(x1, 26); x1 ^= x0;
  x0 += x1; x1 = rotl32(x1,  6); x1 ^= x0;
  x0 += k1; x1 += k2 + 1u;
  x0 += x1; x1 = rotl32(x1, 17); x1 ^= x0;
  x0 += x1; x1 = rotl32(x1, 29); x1 ^= x0;
  x0 += x1; x1 = rotl32(x1, 16); x1 ^= x0;
  x0 += x1; x1 = rotl32(x1, 24); x1 ^= x0;
  x0 += k2; x1 += k0 + 2u;
  x0 += x1; x1 = rotl32(x1, 13); x1 ^= x0;
  x0 += x1; x1 = rotl32(x1, 15); x1 ^= x0;
  x0 += x1; x1 = rotl32(x1, 26); x1 ^= x0;
  x0 += x1; x1 = rotl32(x1,  6); x1 ^= x0;
  x0 += k0; x1 += k1 + 3u;
  x0 += x1; x1 = rotl32(x1, 17); x1 ^= x0;
  x0 += x1; x1 = rotl32(x1, 29); x1 ^= x0;
  x0 += x1; x1 = rotl32(x1, 16); x1 ^= x0;
  x0 += x1; x1 = rotl32(x1, 24); x1 ^= x0;
  x0 += k1; x1 += k2 + 4u;
  x0 += x1; x1 = rotl32(x1, 13); x1 ^= x0;
  x0 += x1; x1 = rotl32(x1, 15); x1 ^= x0;
  x0 += x1; x1 = rotl32(x1, 26); x1 ^= x0;
  x0 += x1; x1 = rotl32(x1,  6); x1 ^= x0;
  x0 += k2; x1 += k0 + 5u;
  *o0 = x0; *o1 = x1;
}

__device__ __forceinline__ float bits_to_normal(uint32_t b) {
  uint32_t fb = (b >> 9) | 0x3F800000u;
  float f = __uint_as_float(fb) - 1.0f;          // [0,1)
  const float LO = -0.99999994f;                 // nextafter(-1,0)
  float u = f * 2.0f + LO;                       // (hi-lo) == 2.0f in f32
  u = fmaxf(LO, u);
  double zd = 1.4142135623730951 * erfinv((double)u);
  return (float)zd;
}

// PARTITIONABLE threefry (modern JAX default): per-element 64-bit counter
// (hi,lo) = (0,i); 32-bit bits = out0 ^ out1.
__global__ void k_zgen(float* __restrict__ z) {
  int i = blockIdx.x * blockDim.x + threadIdx.x;
  if (i >= 32640) return;
  uint32_t o0, o1;
  threefry2x32(0u, 123u, 0u, (uint32_t)i, &o0, &o1);
  z[i] = bits_to_normal(o0 ^ o1);
}

// ---------------- zero helper ------------------------------------------------
__global__ void k_zero(int* __restrict__ p, int n) {
  for (int i = blockIdx.x * blockDim.x + threadIdx.x; i < n;
       i += gridDim.x * blockDim.x)
    p[i] = 0;
}

// ---------------- CSR build (edge_index int32) ------------------------------
__global__ void k_hist(const int* __restrict__ ei, int* __restrict__ counts) {
  for (int e = blockIdx.x * blockDim.x + threadIdx.x; e < N_EDGES;
       e += gridDim.x * blockDim.x)
    atomicAdd(&counts[ei[N_EDGES + e] & NODE_MASK], 1);
}

__global__ __launch_bounds__(1024) void k_scan(const int* __restrict__ counts,
                                               int* __restrict__ row_ptr) {
  __shared__ int part[1024];
  int t = threadIdx.x;
  const int CH = N_NODES / 1024;  // 32
  int base = t * CH;
  int s = 0;
  for (int i = 0; i < CH; ++i) s += counts[base + i];
  part[t] = s;
  __syncthreads();
  for (int off = 1; off < 1024; off <<= 1) {
    int add = (t >= off) ? part[t - off] : 0;
    __syncthreads();
    part[t] += add;
    __syncthreads();
  }
  int run = (t == 0) ? 0 : part[t - 1];
  for (int i = 0; i < CH; ++i) { row_ptr[base + i] = run; run += counts[base + i]; }
  if (t == 1023) row_ptr[N_NODES] = run;
}

__global__ void k_fill(const int* __restrict__ ei, const int* __restrict__ row_ptr,
                       int* __restrict__ cursor, int* __restrict__ srcs) {
  for (int e = blockIdx.x * blockDim.x + threadIdx.x; e < N_EDGES;
       e += gridDim.x * blockDim.x) {
    int d = ei[N_EDGES + e] & NODE_MASK;
    int pos = row_ptr[d] + atomicAdd(&cursor[d], 1);
    srcs[pos] = ei[e] & NODE_MASK;
  }
}

// ---------------- weight transpose (w[384][128] -> wT[128][384]) ------------
__global__ void k_tr(const float* __restrict__ w_ih, const float* __restrict__ w_hh,
                     float* __restrict__ w_ihT, float* __restrict__ w_hhT) {
  int idx = blockIdx.x * 256 + threadIdx.x;
  if (idx >= 128 * 384) return;
  int k = idx / 384, c = idx % 384;
  w_ihT[idx] = w_ih[c * 128 + k];
  w_hhT[idx] = w_hh[c * 128 + k];
}

// ---------------- lin0: h = sigmoid(x @ lin0_w.T), padded to 128 ------------
__global__ __launch_bounds__(256) void k_lin0(const float* __restrict__ x,
                                              const float* __restrict__ w,
                                              float* __restrict__ h) {
  __shared__ float sw[64][33];
  __shared__ float sx[4][32];
  int t = threadIdx.x;
  for (int e = t; e < 64 * 32; e += 256) sw[e >> 5][e & 31] = w[e];
  int node0 = blockIdx.x * 4;
  if (t < 128) sx[t >> 5][t & 31] = x[node0 * 32 + t];
  __syncthreads();
  int c = t & 63, nl = t >> 6;
  float acc = 0.f;
#pragma unroll
  for (int k = 0; k < 32; ++k) acc += sx[nl][k] * sw[c][k];
  float s = 1.f / (1.f + expf(-acc));
  int n = node0 + nl;
  h[n * 128 + c] = s;
  h[n * 128 + 64 + c] = 0.f;
}

// ---------------- m = h @ G  (G row-major [k][c], 128x128) ------------------
__global__ __launch_bounds__(256) void k_mm(const float* __restrict__ h,
                                            const float* __restrict__ G,
                                            float* __restrict__ m) {
  __shared__ float sh[32][128];
  __shared__ float gB[16][132];
  int t = threadIdx.x;
  int node0 = blockIdx.x * 32;
  for (int e = t; e < 32 * 128; e += 256) sh[e >> 7][e & 127] = h[node0 * 128 + e];
  int cq = (t & 31) * 4;
  int ng = t >> 5;  // 0..7, 4 nodes each
  float4 acc[4];
#pragma unroll
  for (int nd = 0; nd < 4; ++nd) acc[nd] = make_float4(0.f, 0.f, 0.f, 0.f);
  for (int k0 = 0; k0 < 128; k0 += 16) {
    __syncthreads();
    for (int e = t; e < 16 * 128; e += 256)
      gB[e >> 7][e & 127] = G[(k0 + (e >> 7)) * 128 + (e & 127)];
    __syncthreads();
#pragma unroll
    for (int kk = 0; kk < 16; ++kk) {
      float4 b = *(const float4*)&gB[kk][cq];
#pragma unroll
      for (int nd = 0; nd < 4; ++nd) {
        float a = sh[ng * 4 + nd][k0 + kk];
        acc[nd].x += a * b.x; acc[nd].y += a * b.y;
        acc[nd].z += a * b.z; acc[nd].w += a * b.w;
      }
    }
  }
#pragma unroll
  for (int nd = 0; nd < 4; ++nd)
    *(float4*)&m[(node0 + ng * 4 + nd) * 128 + cq] = acc[nd];
}

// ---------------- segment-sum gather ----------------------------------------
__global__ void k_agg(const float* __restrict__ m, float* __restrict__ magg,
                      const int* __restrict__ row_ptr, const int* __restrict__ srcs) {
  int wid = (blockIdx.x * blockDim.x + threadIdx.x) >> 6;  // node = global wave
  int lane = threadIdx.x & 63;
  if (wid >= N_NODES) return;
  int beg = row_ptr[wid], end = row_ptr[wid + 1];
  float2 acc = make_float2(0.f, 0.f);
  for (int e = beg; e < end; ++e) {
    int s = srcs[e] & NODE_MASK;
    float2 v = *(const float2*)&m[s * 128 + lane * 2];
    acc.x += v.x; acc.y += v.y;
  }
  *(float2*)&magg[wid * 128 + lane * 2] = acc;
}

// ---------------- fused GRU cell: h = GRU(magg, h), in place ----------------
__global__ __launch_bounds__(256) void k_gru(const float* __restrict__ magg,
                                             float* __restrict__ h,
                                             const float* __restrict__ w_ihT,
                                             const float* __restrict__ w_hhT,
                                             const float* __restrict__ b_ih,
                                             const float* __restrict__ b_hh) {
  __shared__ float sm[32][128];
  __shared__ float shh[32][128];
  __shared__ float sw1[16][130];
  __shared__ float sw2[16][130];
  int t = threadIdx.x;
  int node0 = blockIdx.x * 32;
  for (int e = t; e < 32 * 128; e += 256) {
    sm[e >> 7][e & 127]  = magg[node0 * 128 + e];
    shh[e >> 7][e & 127] = h[node0 * 128 + e];
  }
  int cp = (t & 63) * 2;      // column pair
  int nb = (t >> 6) * 8;      // 8 nodes per thread
  float r[8][2], zg[8][2];
  for (int gate = 0; gate < 3; ++gate) {
    float ai[8][2], ah[8][2];
    float bi0 = b_ih[gate * 128 + cp], bi1 = b_ih[gate * 128 + cp + 1];
    float bh0 = b_hh[gate * 128 + cp], bh1 = b_hh[gate * 128 + cp + 1];
#pragma unroll
    for (int nd = 0; nd < 8; ++nd) {
      ai[nd][0] = bi0; ai[nd][1] = bi1;
      ah[nd][0] = bh0; ah[nd][1] = bh1;
    }
    for (int k0 = 0; k0 < 128; k0 += 16) {
      __syncthreads();
      for (int e = t; e < 16 * 128; e += 256) {
        int kk = e >> 7, c = e & 127;
        sw1[kk][c] = w_ihT[(k0 + kk) * 384 + gate * 128 + c];
        sw2[kk][c] = w_hhT[(k0 + kk) * 384 + gate * 128 + c];
      }
      __syncthreads();
#pragma unroll
      for (int kq = 0; kq < 4; ++kq) {
        float4 mq[8], hq[8];
#pragma unroll
        for (int nd = 0; nd < 8; ++nd) {
          mq[nd] = *(const float4*)&sm[nb + nd][k0 + kq * 4];
          hq[nd] = *(const float4*)&shh[nb + nd][k0 + kq * 4];
        }
#pragma unroll
        for (int q = 0; q < 4; ++q) {
          float2 w1 = *(const float2*)&sw1[kq * 4 + q][cp];
          float2 w2 = *(const float2*)&sw2[kq * 4 + q][cp];
#pragma unroll
          for (int nd = 0; nd < 8; ++nd) {
            float mv = (q == 0) ? mq[nd].x : (q == 1) ? mq[nd].y : (q == 2) ? mq[nd].z : mq[nd].w;
            float hv = (q == 0) ? hq[nd].x : (q == 1) ? hq[nd].y : (q == 2) ? hq[nd].z : hq[nd].w;
            ai[nd][0] += mv * w1.x; ai[nd][1] += mv * w1.y;
            ah[nd][0] += hv * w2.x; ah[nd][1] += hv * w2.y;
          }
        }
      }
    }
    if (gate == 0) {
#pragma unroll
      for (int nd = 0; nd < 8; ++nd) {
        r[nd][0] = 1.f / (1.f + expf(-(ai[nd][0] + ah[nd][0])));
        r[nd][1] = 1.f / (1.f + expf(-(ai[nd][1] + ah[nd][1])));
      }
    } else if (gate == 1) {
#pragma unroll
      for (int nd = 0; nd < 8; ++nd) {
        zg[nd][0] = 1.f / (1.f + expf(-(ai[nd][0] + ah[nd][0])));
        zg[nd][1] = 1.f / (1.f + expf(-(ai[nd][1] + ah[nd][1])));
      }
    } else {
#pragma unroll
      for (int nd = 0; nd < 8; ++nd) {
        float n0 = tanhf(ai[nd][0] + r[nd][0] * ah[nd][0]);
        float n1 = tanhf(ai[nd][1] + r[nd][1] * ah[nd][1]);
        float hp0 = shh[nb + nd][cp], hp1 = shh[nb + nd][cp + 1];
        float2 o;
        o.x = (1.f - zg[nd][0]) * n0 + zg[nd][0] * hp0;
        o.y = (1.f - zg[nd][1]) * n1 + zg[nd][1] * hp1;
        *(float2*)&h[(node0 + nb + nd) * 128 + cp] = o;
      }
    }
  }
}

// ---------------- heads ------------------------------------------------------
__global__ __launch_bounds__(256) void k_musig(const float* __restrict__ h,
                                               const float* __restrict__ w1,
                                               const float* __restrict__ b1,
                                               const float* __restrict__ w2,
                                               const float* __restrict__ b2,
                                               float* __restrict__ mu,
                                               float* __restrict__ sigma) {
  int t = threadIdx.x;
  int lane = t & 63, wv = t >> 6;
  int n = blockIdx.x * 4 + wv;
  float2 hv = *(const float2*)&h[n * 128 + lane * 2];
  hv.x = fmaxf(hv.x, 0.f); hv.y = fmaxf(hv.y, 0.f);
  float2 w1v = *(const float2*)&w1[lane * 2];
  float2 w2v = *(const float2*)&w2[lane * 2];
  float a = hv.x * w1v.x + hv.y * w1v.y;
  float b = hv.x * w2v.x + hv.y * w2v.y;
#pragma unroll
  for (int off = 32; off > 0; off >>= 1) {
    a += __shfl_down(a, off);
    b += __shfl_down(b, off);
  }
  if (lane == 0) {
    mu[n] = a + b1[0];
    float v = b + b2[0];
    sigma[n] = fmaxf(v, 0.f) + log1pf(expf(-fabsf(v)));  // softplus, stable
  }
}

// ---------------- sampler (fp64 internal): analytic Cholesky ----------------
__device__ __forceinline__ double dscan_incl(double v, volatile double* buf, int i,
                                             double* tot) {
  buf[i] = v;
  __syncthreads();
#pragma unroll
  for (int off = 1; off < 256; off <<= 1) {
    double add = (i >= off) ? buf[i - off] : 0.0;
    __syncthreads();
    buf[i] += add;
    __syncthreads();
  }
  double incl = buf[i];
  *tot = buf[255];
  __syncthreads();
  return incl;
}

__global__ __launch_bounds__(256) void k_sample(const float* __restrict__ mu,
                                                const float* __restrict__ sigma,
                                                const float* __restrict__ zbuf,
                                                float* __restrict__ out) {
  __shared__ double buf[256];
  __shared__ double lastd[2];
  int g = blockIdx.x, i = threadIdx.x;
  int n = (g << 8) + i;
  double sig = (double)sigma[n], muv = (double)mu[n];
  bool isLast = (i == 255);
  if (isLast) { lastd[0] = sig; lastd[1] = muv; }
  double s   = isLast ? 0.0 : sig;
  double mui = isLast ? 0.0 : muv;
  double tS, tM, tY, tX;
  double inclS = dscan_incl(s, buf, i, &tS);
  dscan_incl(mui, buf, i, &tM);
  double sigLast = lastd[0], muLast = lastd[1];
  double denom = tS + sigLast;
  double c = -muLast / sigLast;                 // (K - mu_last)/sigma_last, K=0
  double pre = inclS - s;                       // exclusive prefix of s
  double suffix  = denom - pre;                 // sigma_last + sum_{k>=i} s_k
  double suffix1 = suffix - s;
  double sigL = isLast ? 0.0 : sqrt(s * suffix1 / suffix);   // L_ii
  double cL   = isLast ? 0.0 : (-s / (suffix * sigL));       // L_ji = cL_i*s_j
  double zv   = isLast ? 0.0 : (double)zbuf[g * 255 + i];
  double y = cL * zv;
  double inclY = dscan_incl(y, buf, i, &tY);
  double Pz = inclY - y;                        // sum_{j<i} cL_j z_j
  double rm = s * c + mui - s * (c * tS + tM) / denom;   // (cov @ rhs)_i
  double X = rm + s * Pz + sigL * zv;
  if (isLast) X = 0.0;
  dscan_incl(X, buf, i, &tX);
  out[n] = (float)(isLast ? (0.0 - tX) : X);    // last = K - sum(X), K=0
}

// ---------------------------------------------------------------------------
extern "C" void kernel_launch(void* const* d_in, const int* in_sizes, int n_in,
                              void* d_out, int out_size, void* d_ws, size_t ws_size,
                              hipStream_t stream) {
  const float* x      = (const float*)d_in[0];
  const float* lin0_w = (const float*)d_in[1];
  const float* ggc_w  = (const float*)d_in[2];
  const float* w_ih   = (const float*)d_in[3];
  const float* w_hh   = (const float*)d_in[4];
  const float* b_ih   = (const float*)d_in[5];
  const float* b_hh   = (const float*)d_in[6];
  const float* lin1_w = (const float*)d_in[7];
  const float* lin1_b = (const float*)d_in[8];
  const float* lin2_w = (const float*)d_in[9];
  const float* lin2_b = (const float*)d_in[10];
  const int*   ei     = (const int*)d_in[11];   // int32 per harness contract
  float* out = (float*)d_out;

  char* ws = (char*)d_ws;
  float* h     = (float*)(ws + 0);          // 16 MB
  float* m     = (float*)(ws + 16777216);   // 16 MB
  float* magg  = (float*)(ws + 33554432);   // 16 MB
  float* w_ihT = (float*)(ws + 50331648);   // 192 KB
  float* w_hhT = (float*)(ws + 50528256);   // 192 KB
  float* zbuf  = (float*)(ws + 50724864);   // 130,560 B (slot 128KB)
  float* mu    = (float*)(ws + 50855936);   // 128 KB
  float* sigma = (float*)(ws + 50987008);   // 128 KB
  int* row_ptr = (int*)(ws + 51118080);     // 128.5 KB
  int* counts  = (int*)(ws + 51249664);     // 128 KB (reused as cursor)
  int* srcs    = (int*)(ws + 51380736);     // 2 MB
  const size_t WS_NEEDED = 53477888;
  if (ws_size < WS_NEEDED) return;

  // CSR build
  k_zero<<<32, 256, 0, stream>>>(counts, N_NODES);
  k_hist<<<1024, 256, 0, stream>>>(ei, counts);
  k_scan<<<1, 1024, 0, stream>>>(counts, row_ptr);
  k_zero<<<32, 256, 0, stream>>>(counts, N_NODES);
  k_fill<<<1024, 256, 0, stream>>>(ei, row_ptr, counts, srcs);

  k_tr<<<192, 256, 0, stream>>>(w_ih, w_hh, w_ihT, w_hhT);
  k_zgen<<<128, 256, 0, stream>>>(zbuf);
  k_lin0<<<8192, 256, 0, stream>>>(x, lin0_w, h);

  for (int L = 0; L < 4; ++L) {
    k_mm<<<1024, 256, 0, stream>>>(h, ggc_w + (size_t)L * 128 * 128, m);
    k_agg<<<8192, 256, 0, stream>>>(m, magg, row_ptr, srcs);
    k_gru<<<1024, 256, 0, stream>>>(magg, h, w_ihT, w_hhT, b_ih, b_hh);
  }

  k_musig<<<8192, 256, 0, stream>>>(h, lin1_w, lin1_b, lin2_w, lin2_b, mu, sigma);
  k_sample<<<128, 256, 0, stream>>>(mu, sigma, zbuf, out);
}

// Round 7
// 795.749 us; speedup vs baseline: 1.3631x; 1.3631x over previous
//
#include <hip/hip_runtime.h>
#include <stdint.h>

#define N_NODES 32768
#define N_EDGES 524288
#define NODE_MASK (N_NODES - 1)

typedef __attribute__((ext_vector_type(8))) short bf16x8;
typedef __attribute__((ext_vector_type(4))) float f32x4;
typedef unsigned short ushort_t;

__device__ __forceinline__ ushort_t f2b(float f) {  // f32 -> bf16 RNE
  uint32_t u = __float_as_uint(f);
  return (ushort_t)((u + 0x7FFFu + ((u >> 16) & 1u)) >> 16);
}
__device__ __forceinline__ float b2f(uint32_t lo16) {
  return __uint_as_float(lo16 << 16);
}

// ---------------- threefry2x32 (Threefry-20, partitionable mode) ------------
__device__ __forceinline__ uint32_t rotl32(uint32_t v, int r) {
  return (v << r) | (v >> (32 - r));
}

__device__ __forceinline__ void threefry2x32(uint32_t k0, uint32_t k1,
                                             uint32_t x0, uint32_t x1,
                                             uint32_t* o0, uint32_t* o1) {
  uint32_t k2 = k0 ^ k1 ^ 0x1BD11BDAu;
  x0 += k0; x1 += k1;
  x0 += x1; x1 = rotl32(x1, 13); x1 ^= x0;
  x0 += x1; x1 = rotl32(x1, 15); x1 ^= x0;
  x0 += x1; x1 = rotl32(x1, 26); x1 ^= x0;
  x0 += x1; x1 = rotl32(x1,  6); x1 ^= x0;
  x0 += k1; x1 += k2 + 1u;
  x0 += x1; x1 = rotl32(x1, 17); x1 ^= x0;
  x0 += x1; x1 = rotl32(x1, 29); x1 ^= x0;
  x0 += x1; x1 = rotl32(x1, 16); x1 ^= x0;
  x0 += x1; x1 = rotl32(x1, 24); x1 ^= x0;
  x0 += k2; x1 += k0 + 2u;
  x0 += x1; x1 = rotl32(x1, 13); x1 ^= x0;
  x0 += x1; x1 = rotl32(x1, 15); x1 ^= x0;
  x0 += x1; x1 = rotl32(x1, 26); x1 ^= x0;
  x0 += x1; x1 = rotl32(x1,  6); x1 ^= x0;
  x0 += k0; x1 += k1 + 3u;
  x0 += x1; x1 = rotl32(x1, 17); x1 ^= x0;
  x0 += x1; x1 = rotl32(x1, 29); x1 ^= x0;
  x0 += x1; x1 = rotl32(x1, 16); x1 ^= x0;
  x0 += x1; x1 = rotl32(x1, 24); x1 ^= x0;
  x0 += k1; x1 += k2 + 4u;
  x0 += x1; x1 = rotl32(x1, 13); x1 ^= x0;
  x0 += x1; x1 = rotl32(x1, 15); x1 ^= x0;
  x0 += x1; x1 = rotl32(x1, 26); x1 ^= x0;
  x0 += x1; x1 = rotl32(x1,  6); x1 ^= x0;
  x0 += k2; x1 += k0 + 5u;
  *o0 = x0; *o1 = x1;
}

__device__ __forceinline__ float bits_to_normal(uint32_t b) {
  uint32_t fb = (b >> 9) | 0x3F800000u;
  float f = __uint_as_float(fb) - 1.0f;          // [0,1)
  const float LO = -0.99999994f;
  float u = f * 2.0f + LO;
  u = fmaxf(LO, u);
  double zd = 1.4142135623730951 * erfinv((double)u);
  return (float)zd;
}

__global__ void k_zgen(float* __restrict__ z) {
  int i = blockIdx.x * blockDim.x + threadIdx.x;
  if (i >= 32640) return;
  uint32_t o0, o1;
  threefry2x32(0u, 123u, 0u, (uint32_t)i, &o0, &o1);
  z[i] = bits_to_normal(o0 ^ o1);
}

// ---------------- zero helper ------------------------------------------------
__global__ void k_zero(int* __restrict__ p, int n) {
  for (int i = blockIdx.x * blockDim.x + threadIdx.x; i < n;
       i += gridDim.x * blockDim.x)
    p[i] = 0;
}

// ---------------- CSR build (edge_index int32) ------------------------------
__global__ void k_hist(const int* __restrict__ ei, int* __restrict__ counts) {
  for (int e = blockIdx.x * blockDim.x + threadIdx.x; e < N_EDGES;
       e += gridDim.x * blockDim.x)
    atomicAdd(&counts[ei[N_EDGES + e] & NODE_MASK], 1);
}

__global__ __launch_bounds__(1024) void k_scan(const int* __restrict__ counts,
                                               int* __restrict__ row_ptr) {
  __shared__ int part[1024];
  int t = threadIdx.x;
  const int CH = N_NODES / 1024;  // 32
  int base = t * CH;
  int s = 0;
  for (int i = 0; i < CH; ++i) s += counts[base + i];
  part[t] = s;
  __syncthreads();
  for (int off = 1; off < 1024; off <<= 1) {
    int add = (t >= off) ? part[t - off] : 0;
    __syncthreads();
    part[t] += add;
    __syncthreads();
  }
  int run = (t == 0) ? 0 : part[t - 1];
  for (int i = 0; i < CH; ++i) { row_ptr[base + i] = run; run += counts[base + i]; }
  if (t == 1023) row_ptr[N_NODES] = run;
}

__global__ void k_fill(const int* __restrict__ ei, const int* __restrict__ row_ptr,
                       int* __restrict__ cursor, int* __restrict__ srcs) {
  for (int e = blockIdx.x * blockDim.x + threadIdx.x; e < N_EDGES;
       e += gridDim.x * blockDim.x) {
    int d = ei[N_EDGES + e] & NODE_MASK;
    int pos = row_ptr[d] + atomicAdd(&cursor[d], 1);
    srcs[pos] = ei[e] & NODE_MASK;
  }
}

// ---------------- weight prep: f32 -> (hi,lo) bf16 planes, [384][128] -------
__global__ void k_wprep(const float* __restrict__ w_ih, const float* __restrict__ w_hh,
                        ushort_t* __restrict__ wihH, ushort_t* __restrict__ wihL,
                        ushort_t* __restrict__ whhH, ushort_t* __restrict__ whhL) {
  int i = blockIdx.x * 256 + threadIdx.x;
  if (i >= 384 * 128) return;
  float a = w_ih[i];
  ushort_t ah = f2b(a);
  wihH[i] = ah; wihL[i] = f2b(a - b2f(ah));
  float b = w_hh[i];
  ushort_t bh = f2b(b);
  whhH[i] = bh; whhL[i] = f2b(b - b2f(bh));
}

// ---------------- G prep: GT[L][c][k] hi/lo planes from ggc_w[L][k][c] ------
__global__ void k_gprep(const float* __restrict__ G,
                        ushort_t* __restrict__ GH, ushort_t* __restrict__ GL) {
  int i = blockIdx.x * 256 + threadIdx.x;
  if (i >= 4 * 128 * 128) return;
  int L = i >> 14, j = i & 16383;
  int c = j >> 7, k = j & 127;
  float g = G[L * 16384 + k * 128 + c];
  ushort_t gh = f2b(g);
  GH[i] = gh; GL[i] = f2b(g - b2f(gh));
}

// ---------------- lin0: h = sigmoid(x @ lin0_w.T) -> hi/lo planes, pad ------
__global__ __launch_bounds__(256) void k_lin0(const float* __restrict__ x,
                                              const float* __restrict__ w,
                                              ushort_t* __restrict__ hH,
                                              ushort_t* __restrict__ hL) {
  __shared__ float sw[64][33];
  __shared__ float sx[4][32];
  int t = threadIdx.x;
  for (int e = t; e < 64 * 32; e += 256) sw[e >> 5][e & 31] = w[e];
  int node0 = blockIdx.x * 4;
  if (t < 128) sx[t >> 5][t & 31] = x[node0 * 32 + t];
  __syncthreads();
  int c = t & 63, nl = t >> 6;
  float acc = 0.f;
#pragma unroll
  for (int k = 0; k < 32; ++k) acc += sx[nl][k] * sw[c][k];
  float s = 1.f / (1.f + expf(-acc));
  int n = node0 + nl;
  ushort_t sh = f2b(s);
  hH[n * 128 + c] = sh;
  hL[n * 128 + c] = f2b(s - b2f(sh));
  hH[n * 128 + 64 + c] = 0;
  hL[n * 128 + 64 + c] = 0;
}

// ---------------- m = h @ G via 3-term split MFMA; output f32 ---------------
__global__ __launch_bounds__(256) void k_mm_mfma(const ushort_t* __restrict__ hH,
                                                 const ushort_t* __restrict__ hL,
                                                 const ushort_t* __restrict__ GH,
                                                 const ushort_t* __restrict__ GL,
                                                 float* __restrict__ m) {
  int t = threadIdx.x;
  int w = t >> 6, l = t & 63;
  int node0 = blockIdx.x * 64 + w * 16;
  int ar = l & 15, ak = (l >> 4) * 8;
  bf16x8 aH[4], aL[4];
#pragma unroll
  for (int kk = 0; kk < 4; ++kk) {
    aH[kk] = *(const bf16x8*)&hH[(node0 + ar) * 128 + kk * 32 + ak];
    aL[kk] = *(const bf16x8*)&hL[(node0 + ar) * 128 + kk * 32 + ak];
  }
#pragma unroll
  for (int nt = 0; nt < 8; ++nt) {
    f32x4 acc = {0.f, 0.f, 0.f, 0.f};
#pragma unroll
    for (int kk = 0; kk < 4; ++kk) {
      int bo = (nt * 16 + ar) * 128 + kk * 32 + ak;
      bf16x8 bH = *(const bf16x8*)&GH[bo];
      bf16x8 bL = *(const bf16x8*)&GL[bo];
      acc = __builtin_amdgcn_mfma_f32_16x16x32_bf16(aH[kk], bH, acc, 0, 0, 0);
      acc = __builtin_amdgcn_mfma_f32_16x16x32_bf16(aH[kk], bL, acc, 0, 0, 0);
      acc = __builtin_amdgcn_mfma_f32_16x16x32_bf16(aL[kk], bH, acc, 0, 0, 0);
    }
    int col = nt * 16 + ar;
#pragma unroll
    for (int j = 0; j < 4; ++j) {
      int row = (l >> 4) * 4 + j;
      m[(node0 + row) * 128 + col] = acc[j];
    }
  }
}

// ---------------- segment-sum gather: f32 in, hi/lo planes out --------------
__global__ void k_agg(const float* __restrict__ m,
                      ushort_t* __restrict__ mgH, ushort_t* __restrict__ mgL,
                      const int* __restrict__ row_ptr, const int* __restrict__ srcs) {
  int wid = (blockIdx.x * blockDim.x + threadIdx.x) >> 6;
  int lane = threadIdx.x & 63;
  if (wid >= N_NODES) return;
  int beg = row_ptr[wid], end = row_ptr[wid + 1];
  float ax = 0.f, ay = 0.f;
  for (int e = beg; e < end; ++e) {
    int s = srcs[e] & NODE_MASK;
    float2 v = *(const float2*)&m[s * 128 + lane * 2];
    ax += v.x; ay += v.y;
  }
  ushort_t xh = f2b(ax), yh = f2b(ay);
  ushort_t xl = f2b(ax - b2f(xh)), yl = f2b(ay - b2f(yh));
  *(uint32_t*)&mgH[wid * 128 + lane * 2] = (uint32_t)xh | ((uint32_t)yh << 16);
  *(uint32_t*)&mgL[wid * 128 + lane * 2] = (uint32_t)xl | ((uint32_t)yl << 16);
}

// ---------------- fused GRU via 3-term split MFMA ---------------------------
__global__ __launch_bounds__(256) void k_gru_mfma(
    const ushort_t* __restrict__ mgH, const ushort_t* __restrict__ mgL,
    ushort_t* __restrict__ hH, ushort_t* __restrict__ hL,
    const ushort_t* __restrict__ wihH, const ushort_t* __restrict__ wihL,
    const ushort_t* __restrict__ whhH, const ushort_t* __restrict__ whhL,
    const float* __restrict__ b_ih, const float* __restrict__ b_hh) {
  int t = threadIdx.x;
  int w = t >> 6, l = t & 63;
  int node0 = blockIdx.x * 64 + w * 16;
  int ar = l & 15, ak = (l >> 4) * 8;
  bf16x8 amH[4], amL[4], ahH[4], ahL[4];
#pragma unroll
  for (int kk = 0; kk < 4; ++kk) {
    int o = (node0 + ar) * 128 + kk * 32 + ak;
    amH[kk] = *(const bf16x8*)&mgH[o];
    amL[kk] = *(const bf16x8*)&mgL[o];
    ahH[kk] = *(const bf16x8*)&hH[o];
    ahL[kk] = *(const bf16x8*)&hL[o];
  }
  // all A-frag + hp reads of this block's tile complete before any writes
  __syncthreads();
#pragma unroll
  for (int ct = 0; ct < 8; ++ct) {
    f32x4 air = {0.f,0.f,0.f,0.f}, aiz = air, ain = air;
    f32x4 ahr = air, ahz = air, ahn = air;
    int c0 = ct * 16 + ar;
#pragma unroll
    for (int kk = 0; kk < 4; ++kk) {
      int ko = kk * 32 + ak;
      {
        bf16x8 bH = *(const bf16x8*)&wihH[(c0      ) * 128 + ko];
        bf16x8 bL = *(const bf16x8*)&wihL[(c0      ) * 128 + ko];
        air = __builtin_amdgcn_mfma_f32_16x16x32_bf16(amH[kk], bH, air, 0, 0, 0);
        air = __builtin_amdgcn_mfma_f32_16x16x32_bf16(amH[kk], bL, air, 0, 0, 0);
        air = __builtin_amdgcn_mfma_f32_16x16x32_bf16(amL[kk], bH, air, 0, 0, 0);
      }
      {
        bf16x8 bH = *(const bf16x8*)&wihH[(c0 + 128) * 128 + ko];
        bf16x8 bL = *(const bf16x8*)&wihL[(c0 + 128) * 128 + ko];
        aiz = __builtin_amdgcn_mfma_f32_16x16x32_bf16(amH[kk], bH, aiz, 0, 0, 0);
        aiz = __builtin_amdgcn_mfma_f32_16x16x32_bf16(amH[kk], bL, aiz, 0, 0, 0);
        aiz = __builtin_amdgcn_mfma_f32_16x16x32_bf16(amL[kk], bH, aiz, 0, 0, 0);
      }
      {
        bf16x8 bH = *(const bf16x8*)&wihH[(c0 + 256) * 128 + ko];
        bf16x8 bL = *(const bf16x8*)&wihL[(c0 + 256) * 128 + ko];
        ain = __builtin_amdgcn_mfma_f32_16x16x32_bf16(amH[kk], bH, ain, 0, 0, 0);
        ain = __builtin_amdgcn_mfma_f32_16x16x32_bf16(amH[kk], bL, ain, 0, 0, 0);
        ain = __builtin_amdgcn_mfma_f32_16x16x32_bf16(amL[kk], bH, ain, 0, 0, 0);
      }
      {
        bf16x8 bH = *(const bf16x8*)&whhH[(c0      ) * 128 + ko];
        bf16x8 bL = *(const bf16x8*)&whhL[(c0      ) * 128 + ko];
        ahr = __builtin_amdgcn_mfma_f32_16x16x32_bf16(ahH[kk], bH, ahr, 0, 0, 0);
        ahr = __builtin_amdgcn_mfma_f32_16x16x32_bf16(ahH[kk], bL, ahr, 0, 0, 0);
        ahr = __builtin_amdgcn_mfma_f32_16x16x32_bf16(ahL[kk], bH, ahr, 0, 0, 0);
      }
      {
        bf16x8 bH = *(const bf16x8*)&whhH[(c0 + 128) * 128 + ko];
        bf16x8 bL = *(const bf16x8*)&whhL[(c0 + 128) * 128 + ko];
        ahz = __builtin_amdgcn_mfma_f32_16x16x32_bf16(ahH[kk], bH, ahz, 0, 0, 0);
        ahz = __builtin_amdgcn_mfma_f32_16x16x32_bf16(ahH[kk], bL, ahz, 0, 0, 0);
        ahz = __builtin_amdgcn_mfma_f32_16x16x32_bf16(ahL[kk], bH, ahz, 0, 0, 0);
      }
      {
        bf16x8 bH = *(const bf16x8*)&whhH[(c0 + 256) * 128 + ko];
        bf16x8 bL = *(const bf16x8*)&whhL[(c0 + 256) * 128 + ko];
        ahn = __builtin_amdgcn_mfma_f32_16x16x32_bf16(ahH[kk], bH, ahn, 0, 0, 0);
        ahn = __builtin_amdgcn_mfma_f32_16x16x32_bf16(ahH[kk], bL, ahn, 0, 0, 0);
        ahn = __builtin_amdgcn_mfma_f32_16x16x32_bf16(ahL[kk], bH, ahn, 0, 0, 0);
      }
    }
    int col = c0;
    float bir = b_ih[col], biz = b_ih[128 + col], bin = b_ih[256 + col];
    float bhr = b_hh[col], bhz = b_hh[128 + col], bhn = b_hh[256 + col];
#pragma unroll
    for (int j = 0; j < 4; ++j) {
      int row = node0 + (l >> 4) * 4 + j;
      int idx = row * 128 + col;
      float gr = air[j] + bir + ahr[j] + bhr;
      float gz = aiz[j] + biz + ahz[j] + bhz;
      float r  = 1.f / (1.f + expf(-gr));
      float zg = 1.f / (1.f + expf(-gz));
      float nn = tanhf(ain[j] + bin + r * (ahn[j] + bhn));
      float hp = b2f(hH[idx]) + b2f(hL[idx]);   // own (row,col): no race
      float hn = (1.f - zg) * nn + zg * hp;
      ushort_t hi = f2b(hn);
      hH[idx] = hi;
      hL[idx] = f2b(hn - b2f(hi));
    }
  }
}

// ---------------- heads (h from hi/lo planes) -------------------------------
__global__ __launch_bounds__(256) void k_musig(const ushort_t* __restrict__ hH,
                                               const ushort_t* __restrict__ hL,
                                               const float* __restrict__ w1,
                                               const float* __restrict__ b1,
                                               const float* __restrict__ w2,
                                               const float* __restrict__ b2,
                                               float* __restrict__ mu,
                                               float* __restrict__ sigma) {
  int t = threadIdx.x;
  int lane = t & 63, wv = t >> 6;
  int n = blockIdx.x * 4 + wv;
  uint32_t vh = *(const uint32_t*)&hH[n * 128 + lane * 2];
  uint32_t vl = *(const uint32_t*)&hL[n * 128 + lane * 2];
  float hx = b2f(vh & 0xFFFFu) + b2f(vl & 0xFFFFu);
  float hy = b2f(vh >> 16) + b2f(vl >> 16);
  hx = fmaxf(hx, 0.f); hy = fmaxf(hy, 0.f);
  float2 w1v = *(const float2*)&w1[lane * 2];
  float2 w2v = *(const float2*)&w2[lane * 2];
  float a = hx * w1v.x + hy * w1v.y;
  float b = hx * w2v.x + hy * w2v.y;
#pragma unroll
  for (int off = 32; off > 0; off >>= 1) {
    a += __shfl_down(a, off);
    b += __shfl_down(b, off);
  }
  if (lane == 0) {
    mu[n] = a + b1[0];
    float v = b + b2[0];
    sigma[n] = fmaxf(v, 0.f) + log1pf(expf(-fabsf(v)));
  }
}

// ---------------- sampler (fp64 internal): analytic Cholesky ----------------
__device__ __forceinline__ double dscan_incl(double v, volatile double* buf, int i,
                                             double* tot) {
  buf[i] = v;
  __syncthreads();
#pragma unroll
  for (int off = 1; off < 256; off <<= 1) {
    double add = (i >= off) ? buf[i - off] : 0.0;
    __syncthreads();
    buf[i] += add;
    __syncthreads();
  }
  double incl = buf[i];
  *tot = buf[255];
  __syncthreads();
  return incl;
}

__global__ __launch_bounds__(256) void k_sample(const float* __restrict__ mu,
                                                const float* __restrict__ sigma,
                                                const float* __restrict__ zbuf,
                                                float* __restrict__ out) {
  __shared__ double buf[256];
  __shared__ double lastd[2];
  int g = blockIdx.x, i = threadIdx.x;
  int n = (g << 8) + i;
  double sig = (double)sigma[n], muv = (double)mu[n];
  bool isLast = (i == 255);
  if (isLast) { lastd[0] = sig; lastd[1] = muv; }
  double s   = isLast ? 0.0 : sig;
  double mui = isLast ? 0.0 : muv;
  double tS, tM, tY, tX;
  double inclS = dscan_incl(s, buf, i, &tS);
  dscan_incl(mui, buf, i, &tM);
  double sigLast = lastd[0], muLast = lastd[1];
  double denom = tS + sigLast;
  double c = -muLast / sigLast;
  double pre = inclS - s;
  double suffix  = denom - pre;
  double suffix1 = suffix - s;
  double sigL = isLast ? 0.0 : sqrt(s * suffix1 / suffix);
  double cL   = isLast ? 0.0 : (-s / (suffix * sigL));
  double zv   = isLast ? 0.0 : (double)zbuf[g * 255 + i];
  double y = cL * zv;
  double inclY = dscan_incl(y, buf, i, &tY);
  double Pz = inclY - y;
  double rm = s * c + mui - s * (c * tS + tM) / denom;
  double X = rm + s * Pz + sigL * zv;
  if (isLast) X = 0.0;
  dscan_incl(X, buf, i, &tX);
  out[n] = (float)(isLast ? (0.0 - tX) : X);
}

// ---------------------------------------------------------------------------
extern "C" void kernel_launch(void* const* d_in, const int* in_sizes, int n_in,
                              void* d_out, int out_size, void* d_ws, size_t ws_size,
                              hipStream_t stream) {
  const float* x      = (const float*)d_in[0];
  const float* lin0_w = (const float*)d_in[1];
  const float* ggc_w  = (const float*)d_in[2];
  const float* w_ih   = (const float*)d_in[3];
  const float* w_hh   = (const float*)d_in[4];
  const float* b_ih   = (const float*)d_in[5];
  const float* b_hh   = (const float*)d_in[6];
  const float* lin1_w = (const float*)d_in[7];
  const float* lin1_b = (const float*)d_in[8];
  const float* lin2_w = (const float*)d_in[9];
  const float* lin2_b = (const float*)d_in[10];
  const int*   ei     = (const int*)d_in[11];
  float* out = (float*)d_out;

  char* ws = (char*)d_ws;
  float*    m      = (float*)   (ws + 0);          // 16 MB
  ushort_t* hbH    = (ushort_t*)(ws + 16777216);   // 8 MB
  ushort_t* hbL    = (ushort_t*)(ws + 25165824);   // 8 MB
  ushort_t* mgH    = (ushort_t*)(ws + 33554432);   // 8 MB
  ushort_t* mgL    = (ushort_t*)(ws + 41943040);   // 8 MB
  ushort_t* wihH   = (ushort_t*)(ws + 50331648);   // 96 KB
  ushort_t* wihL   = (ushort_t*)(ws + 50429952);   // 96 KB
  ushort_t* whhH   = (ushort_t*)(ws + 50528256);   // 96 KB
  ushort_t* whhL   = (ushort_t*)(ws + 50626560);   // 96 KB
  ushort_t* GH     = (ushort_t*)(ws + 50724864);   // 128 KB [mu aliases]
  ushort_t* GL     = (ushort_t*)(ws + 50855936);   // 128 KB
  float*    zbuf   = (float*)   (ws + 50987008);   // 128 KB [counts aliases]
  float*    sigma  = (float*)   (ws + 51118080);   // 128 KB
  int*      row_ptr= (int*)     (ws + 51249152);   // 128.5 KB slot
  int*      srcs   = (int*)     (ws + 51380736);   // 2 MB
  float*    mu     = (float*)GH;                   // alias: k_musig after all k_mm
  int*      counts = (int*)zbuf;                   // alias: CSR build before k_zgen
  const size_t WS_NEEDED = 53477888;               // proven available (r4/r5)
  if (ws_size < WS_NEEDED) return;

  // CSR build (counts aliases zbuf; done before k_zgen)
  k_zero<<<32, 256, 0, stream>>>(counts, N_NODES);
  k_hist<<<1024, 256, 0, stream>>>(ei, counts);
  k_scan<<<1, 1024, 0, stream>>>(counts, row_ptr);
  k_zero<<<32, 256, 0, stream>>>(counts, N_NODES);
  k_fill<<<1024, 256, 0, stream>>>(ei, row_ptr, counts, srcs);

  k_wprep<<<192, 256, 0, stream>>>(w_ih, w_hh, wihH, wihL, whhH, whhL);
  k_gprep<<<256, 256, 0, stream>>>(ggc_w, GH, GL);
  k_zgen<<<128, 256, 0, stream>>>(zbuf);
  k_lin0<<<8192, 256, 0, stream>>>(x, lin0_w, hbH, hbL);

  for (int L = 0; L < 4; ++L) {
    k_mm_mfma<<<512, 256, 0, stream>>>(hbH, hbL, GH + (size_t)L * 16384,
                                       GL + (size_t)L * 16384, m);
    k_agg<<<8192, 256, 0, stream>>>(m, mgH, mgL, row_ptr, srcs);
    k_gru_mfma<<<512, 256, 0, stream>>>(mgH, mgL, hbH, hbL,
                                        wihH, wihL, whhH, whhL, b_ih, b_hh);
  }

  k_musig<<<8192, 256, 0, stream>>>(hbH, hbL, lin1_w, lin1_b, lin2_w, lin2_b,
                                    mu, sigma);
  k_sample<<<128, 256, 0, stream>>>(mu, sigma, zbuf, out);
}

// Round 8
// 598.106 us; speedup vs baseline: 1.8136x; 1.3304x over previous
//
#include <hip/hip_runtime.h>
#include <stdint.h>

#define N_NODES 32768
#define N_EDGES 524288
#define NODE_MASK (N_NODES - 1)

typedef __attribute__((ext_vector_type(8))) short bf16x8;
typedef __attribute__((ext_vector_type(4))) float f32x4;
typedef unsigned short ushort_t;

__device__ __forceinline__ ushort_t f2b(float f) {  // f32 -> bf16 RNE
  uint32_t u = __float_as_uint(f);
  return (ushort_t)((u + 0x7FFFu + ((u >> 16) & 1u)) >> 16);
}
__device__ __forceinline__ float b2f(uint32_t lo16) {
  return __uint_as_float(lo16 << 16);
}

// ---------------- threefry2x32 (Threefry-20, partitionable mode) ------------
__device__ __forceinline__ uint32_t rotl32(uint32_t v, int r) {
  return (v << r) | (v >> (32 - r));
}

__device__ __forceinline__ void threefry2x32(uint32_t k0, uint32_t k1,
                                             uint32_t x0, uint32_t x1,
                                             uint32_t* o0, uint32_t* o1) {
  uint32_t k2 = k0 ^ k1 ^ 0x1BD11BDAu;
  x0 += k0; x1 += k1;
  x0 += x1; x1 = rotl32(x1, 13); x1 ^= x0;
  x0 += x1; x1 = rotl32(x1, 15); x1 ^= x0;
  x0 += x1; x1 = rotl32(x1, 26); x1 ^= x0;
  x0 += x1; x1 = rotl32(x1,  6); x1 ^= x0;
  x0 += k1; x1 += k2 + 1u;
  x0 += x1; x1 = rotl32(x1, 17); x1 ^= x0;
  x0 += x1; x1 = rotl32(x1, 29); x1 ^= x0;
  x0 += x1; x1 = rotl32(x1, 16); x1 ^= x0;
  x0 += x1; x1 = rotl32(x1, 24); x1 ^= x0;
  x0 += k2; x1 += k0 + 2u;
  x0 += x1; x1 = rotl32(x1, 13); x1 ^= x0;
  x0 += x1; x1 = rotl32(x1, 15); x1 ^= x0;
  x0 += x1; x1 = rotl32(x1, 26); x1 ^= x0;
  x0 += x1; x1 = rotl32(x1,  6); x1 ^= x0;
  x0 += k0; x1 += k1 + 3u;
  x0 += x1; x1 = rotl32(x1, 17); x1 ^= x0;
  x0 += x1; x1 = rotl32(x1, 29); x1 ^= x0;
  x0 += x1; x1 = rotl32(x1, 16); x1 ^= x0;
  x0 += x1; x1 = rotl32(x1, 24); x1 ^= x0;
  x0 += k1; x1 += k2 + 4u;
  x0 += x1; x1 = rotl32(x1, 13); x1 ^= x0;
  x0 += x1; x1 = rotl32(x1, 15); x1 ^= x0;
  x0 += x1; x1 = rotl32(x1, 26); x1 ^= x0;
  x0 += x1; x1 = rotl32(x1,  6); x1 ^= x0;
  x0 += k2; x1 += k0 + 5u;
  *o0 = x0; *o1 = x1;
}

__device__ __forceinline__ float bits_to_normal(uint32_t b) {
  uint32_t fb = (b >> 9) | 0x3F800000u;
  float f = __uint_as_float(fb) - 1.0f;          // [0,1)
  const float LO = -0.99999994f;
  float u = f * 2.0f + LO;
  u = fmaxf(LO, u);
  double zd = 1.4142135623730951 * erfinv((double)u);
  return (float)zd;
}

__global__ void k_zgen(float* __restrict__ z) {
  int i = blockIdx.x * blockDim.x + threadIdx.x;
  if (i >= 32640) return;
  uint32_t o0, o1;
  threefry2x32(0u, 123u, 0u, (uint32_t)i, &o0, &o1);
  z[i] = bits_to_normal(o0 ^ o1);
}

// ---------------- zero helper ------------------------------------------------
__global__ void k_zero(int* __restrict__ p, int n) {
  for (int i = blockIdx.x * blockDim.x + threadIdx.x; i < n;
       i += gridDim.x * blockDim.x)
    p[i] = 0;
}

// ---------------- CSR build (edge_index int32) ------------------------------
__global__ void k_hist(const int* __restrict__ ei, int* __restrict__ counts) {
  for (int e = blockIdx.x * blockDim.x + threadIdx.x; e < N_EDGES;
       e += gridDim.x * blockDim.x)
    atomicAdd(&counts[ei[N_EDGES + e] & NODE_MASK], 1);
}

__global__ __launch_bounds__(1024) void k_scan(const int* __restrict__ counts,
                                               int* __restrict__ row_ptr) {
  __shared__ int part[1024];
  int t = threadIdx.x;
  const int CH = N_NODES / 1024;  // 32
  int base = t * CH;
  int s = 0;
  for (int i = 0; i < CH; ++i) s += counts[base + i];
  part[t] = s;
  __syncthreads();
  for (int off = 1; off < 1024; off <<= 1) {
    int add = (t >= off) ? part[t - off] : 0;
    __syncthreads();
    part[t] += add;
    __syncthreads();
  }
  int run = (t == 0) ? 0 : part[t - 1];
  for (int i = 0; i < CH; ++i) { row_ptr[base + i] = run; run += counts[base + i]; }
  if (t == 1023) row_ptr[N_NODES] = run;
}

__global__ void k_fill(const int* __restrict__ ei, const int* __restrict__ row_ptr,
                       int* __restrict__ cursor, int* __restrict__ srcs) {
  for (int e = blockIdx.x * blockDim.x + threadIdx.x; e < N_EDGES;
       e += gridDim.x * blockDim.x) {
    int d = ei[N_EDGES + e] & NODE_MASK;
    int pos = row_ptr[d] + atomicAdd(&cursor[d], 1);
    srcs[pos] = ei[e] & NODE_MASK;
  }
}

// ---------------- weight prep: f32 -> (hi,lo) bf16 planes, [384][128] -------
__global__ void k_wprep(const float* __restrict__ w_ih, const float* __restrict__ w_hh,
                        ushort_t* __restrict__ wihH, ushort_t* __restrict__ wihL,
                        ushort_t* __restrict__ whhH, ushort_t* __restrict__ whhL) {
  int i = blockIdx.x * 256 + threadIdx.x;
  if (i >= 384 * 128) return;
  float a = w_ih[i];
  ushort_t ah = f2b(a);
  wihH[i] = ah; wihL[i] = f2b(a - b2f(ah));
  float b = w_hh[i];
  ushort_t bh = f2b(b);
  whhH[i] = bh; whhL[i] = f2b(b - b2f(bh));
}

// ---------------- G prep: GT[L][c][k] hi/lo planes from ggc_w[L][k][c] ------
__global__ void k_gprep(const float* __restrict__ G,
                        ushort_t* __restrict__ GH, ushort_t* __restrict__ GL) {
  int i = blockIdx.x * 256 + threadIdx.x;
  if (i >= 4 * 128 * 128) return;
  int L = i >> 14, j = i & 16383;
  int c = j >> 7, k = j & 127;
  float g = G[L * 16384 + k * 128 + c];
  ushort_t gh = f2b(g);
  GH[i] = gh; GL[i] = f2b(g - b2f(gh));
}

// ---------------- lin0: h = sigmoid(x @ lin0_w.T) -> hi/lo planes, pad ------
__global__ __launch_bounds__(256) void k_lin0(const float* __restrict__ x,
                                              const float* __restrict__ w,
                                              ushort_t* __restrict__ hH,
                                              ushort_t* __restrict__ hL) {
  __shared__ float sw[64][33];
  __shared__ float sx[4][32];
  int t = threadIdx.x;
  for (int e = t; e < 64 * 32; e += 256) sw[e >> 5][e & 31] = w[e];
  int node0 = blockIdx.x * 4;
  if (t < 128) sx[t >> 5][t & 31] = x[node0 * 32 + t];
  __syncthreads();
  int c = t & 63, nl = t >> 6;
  float acc = 0.f;
#pragma unroll
  for (int k = 0; k < 32; ++k) acc += sx[nl][k] * sw[c][k];
  float s = 1.f / (1.f + expf(-acc));
  int n = node0 + nl;
  ushort_t sh = f2b(s);
  hH[n * 128 + c] = sh;
  hL[n * 128 + c] = f2b(s - b2f(sh));
  hH[n * 128 + 64 + c] = 0;
  hL[n * 128 + 64 + c] = 0;
}

// ---------------- m = h @ G via 3-term split MFMA; LDS-staged swizzled G ----
__global__ __launch_bounds__(256) void k_mm_mfma(const ushort_t* __restrict__ hH,
                                                 const ushort_t* __restrict__ hL,
                                                 const ushort_t* __restrict__ GH,
                                                 const ushort_t* __restrict__ GL,
                                                 float* __restrict__ m) {
  __shared__ float4 glds4[4096];  // 64 KB: [plane 2][row 128][256 B swizzled]
  int t = threadIdx.x;
  int w = t >> 6, l = t & 63;
  int node0 = blockIdx.x * 64 + w * 16;
  int ar = l & 15, hi = l >> 4, ak = hi * 8;
  bf16x8 aH[4], aL[4];
#pragma unroll
  for (int kk = 0; kk < 4; ++kk) {
    aH[kk] = *(const bf16x8*)&hH[(node0 + ar) * 128 + kk * 32 + ak];
    aL[kk] = *(const bf16x8*)&hL[(node0 + ar) * 128 + kk * 32 + ak];
  }
  // stage G (hi+lo) into LDS, row-XOR-swizzled (16B granules)
#pragma unroll
  for (int i = t; i < 4096; i += 256) {
    int p = i >> 11, chunk = i & 2047;
    const ushort_t* base = p ? GL : GH;
    float4 v = *(const float4*)(base + chunk * 8);
    int row = chunk >> 4, c16 = chunk & 15;
    int byte = p * 32768 + row * 256 + ((c16 * 16) ^ ((row & 7) << 4));
    *(float4*)((char*)glds4 + byte) = v;
  }
  __syncthreads();
  const char* lds = (const char*)glds4;
#pragma unroll
  for (int nt = 0; nt < 8; ++nt) {
    f32x4 acc = {0.f, 0.f, 0.f, 0.f};
    int row = nt * 16 + ar;
    int rbase = row * 256;
    int rsw = (row & 7) << 4;
#pragma unroll
    for (int kk = 0; kk < 4; ++kk) {
      int bin = (kk * 64 + hi * 16) ^ rsw;
      bf16x8 bH = *(const bf16x8*)(lds + rbase + bin);
      bf16x8 bL = *(const bf16x8*)(lds + 32768 + rbase + bin);
      acc = __builtin_amdgcn_mfma_f32_16x16x32_bf16(aH[kk], bH, acc, 0, 0, 0);
      acc = __builtin_amdgcn_mfma_f32_16x16x32_bf16(aH[kk], bL, acc, 0, 0, 0);
      acc = __builtin_amdgcn_mfma_f32_16x16x32_bf16(aL[kk], bH, acc, 0, 0, 0);
    }
    int col = nt * 16 + ar;
#pragma unroll
    for (int j = 0; j < 4; ++j) {
      int orow = hi * 4 + j;
      m[(node0 + orow) * 128 + col] = acc[j];
    }
  }
}

// ---------------- segment-sum gather: f32 in, hi/lo planes out --------------
__global__ void k_agg(const float* __restrict__ m,
                      ushort_t* __restrict__ mgH, ushort_t* __restrict__ mgL,
                      const int* __restrict__ row_ptr, const int* __restrict__ srcs) {
  int wid = (blockIdx.x * blockDim.x + threadIdx.x) >> 6;
  int lane = threadIdx.x & 63;
  if (wid >= N_NODES) return;
  int beg = row_ptr[wid], end = row_ptr[wid + 1];
  float ax = 0.f, ay = 0.f;
  for (int e = beg; e < end; ++e) {
    int s = srcs[e] & NODE_MASK;
    float2 v = *(const float2*)&m[s * 128 + lane * 2];
    ax += v.x; ay += v.y;
  }
  ushort_t xh = f2b(ax), yh = f2b(ay);
  ushort_t xl = f2b(ax - b2f(xh)), yl = f2b(ay - b2f(yh));
  *(uint32_t*)&mgH[wid * 128 + lane * 2] = (uint32_t)xh | ((uint32_t)yh << 16);
  *(uint32_t*)&mgL[wid * 128 + lane * 2] = (uint32_t)xl | ((uint32_t)yl << 16);
}

// ---------------- fused GRU via 3-term split MFMA; LDS-staged weights -------
// Per ct (output col-tile): stage 12 slices [16 rows x 128 k] bf16 (48 KB):
//   s = mtx*6 + gate*2 + plane;  mtx: 0=w_ih 1=w_hh; gate r,z,n; plane H,L.
__global__ __launch_bounds__(256) void k_gru_mfma(
    const ushort_t* __restrict__ mgH, const ushort_t* __restrict__ mgL,
    ushort_t* __restrict__ hH, ushort_t* __restrict__ hL,
    const ushort_t* __restrict__ wihH, const ushort_t* __restrict__ wihL,
    const ushort_t* __restrict__ whhH, const ushort_t* __restrict__ whhL,
    const float* __restrict__ b_ih, const float* __restrict__ b_hh) {
  __shared__ float4 slds4[3072];  // 48 KB
  int t = threadIdx.x;
  int w = t >> 6, l = t & 63;
  int node0 = blockIdx.x * 64 + w * 16;
  int ar = l & 15, hi = l >> 4, ak = hi * 8;
  bf16x8 amH[4], amL[4], ahH[4], ahL[4];
#pragma unroll
  for (int kk = 0; kk < 4; ++kk) {
    int o = (node0 + ar) * 128 + kk * 32 + ak;
    amH[kk] = *(const bf16x8*)&mgH[o];
    amL[kk] = *(const bf16x8*)&mgL[o];
    ahH[kk] = *(const bf16x8*)&hH[o];
    ahL[kk] = *(const bf16x8*)&hL[o];
  }
  const char* lds = (const char*)slds4;
  for (int ct = 0; ct < 8; ++ct) {
    int c0g = ct * 16;
    __syncthreads();  // previous ct's LDS reads complete
    // stage 12 x 4 KB slices, coalesced global reads, swizzled LDS writes
#pragma unroll
    for (int i = t; i < 3072; i += 256) {
      int s = i >> 8, chunk = i & 255;
      int mtx = s / 6, rem = s % 6;
      int gate = rem >> 1, p = rem & 1;
      const ushort_t* base =
          (mtx ? (p ? whhL : whhH) : (p ? wihL : wihH)) + (c0g + gate * 128) * 128;
      float4 v = *(const float4*)(base + chunk * 8);
      int row = chunk >> 4, c16 = chunk & 15;
      int byte = s * 4096 + row * 256 + ((c16 * 16) ^ ((row & 7) << 4));
      *(float4*)((char*)slds4 + byte) = v;
    }
    __syncthreads();
    f32x4 air = {0.f,0.f,0.f,0.f}, aiz = air, ain = air;
    f32x4 ahr = air, ahz = air, ahn = air;
    int rbase = ar * 256;
    int rsw = (ar & 7) << 4;
#pragma unroll
    for (int kk = 0; kk < 4; ++kk) {
      int bin = rbase + ((kk * 64 + hi * 16) ^ rsw);
      bf16x8 B0  = *(const bf16x8*)(lds + 0 * 4096 + bin);
      bf16x8 B1  = *(const bf16x8*)(lds + 1 * 4096 + bin);
      bf16x8 B2  = *(const bf16x8*)(lds + 2 * 4096 + bin);
      bf16x8 B3  = *(const bf16x8*)(lds + 3 * 4096 + bin);
      bf16x8 B4  = *(const bf16x8*)(lds + 4 * 4096 + bin);
      bf16x8 B5  = *(const bf16x8*)(lds + 5 * 4096 + bin);
      bf16x8 B6  = *(const bf16x8*)(lds + 6 * 4096 + bin);
      bf16x8 B7  = *(const bf16x8*)(lds + 7 * 4096 + bin);
      bf16x8 B8  = *(const bf16x8*)(lds + 8 * 4096 + bin);
      bf16x8 B9  = *(const bf16x8*)(lds + 9 * 4096 + bin);
      bf16x8 B10 = *(const bf16x8*)(lds + 10 * 4096 + bin);
      bf16x8 B11 = *(const bf16x8*)(lds + 11 * 4096 + bin);
      air = __builtin_amdgcn_mfma_f32_16x16x32_bf16(amH[kk], B0,  air, 0, 0, 0);
      air = __builtin_amdgcn_mfma_f32_16x16x32_bf16(amH[kk], B1,  air, 0, 0, 0);
      air = __builtin_amdgcn_mfma_f32_16x16x32_bf16(amL[kk], B0,  air, 0, 0, 0);
      aiz = __builtin_amdgcn_mfma_f32_16x16x32_bf16(amH[kk], B2,  aiz, 0, 0, 0);
      aiz = __builtin_amdgcn_mfma_f32_16x16x32_bf16(amH[kk], B3,  aiz, 0, 0, 0);
      aiz = __builtin_amdgcn_mfma_f32_16x16x32_bf16(amL[kk], B2,  aiz, 0, 0, 0);
      ain = __builtin_amdgcn_mfma_f32_16x16x32_bf16(amH[kk], B4,  ain, 0, 0, 0);
      ain = __builtin_amdgcn_mfma_f32_16x16x32_bf16(amH[kk], B5,  ain, 0, 0, 0);
      ain = __builtin_amdgcn_mfma_f32_16x16x32_bf16(amL[kk], B4,  ain, 0, 0, 0);
      ahr = __builtin_amdgcn_mfma_f32_16x16x32_bf16(ahH[kk], B6,  ahr, 0, 0, 0);
      ahr = __builtin_amdgcn_mfma_f32_16x16x32_bf16(ahH[kk], B7,  ahr, 0, 0, 0);
      ahr = __builtin_amdgcn_mfma_f32_16x16x32_bf16(ahL[kk], B6,  ahr, 0, 0, 0);
      ahz = __builtin_amdgcn_mfma_f32_16x16x32_bf16(ahH[kk], B8,  ahz, 0, 0, 0);
      ahz = __builtin_amdgcn_mfma_f32_16x16x32_bf16(ahH[kk], B9,  ahz, 0, 0, 0);
      ahz = __builtin_amdgcn_mfma_f32_16x16x32_bf16(ahL[kk], B8,  ahz, 0, 0, 0);
      ahn = __builtin_amdgcn_mfma_f32_16x16x32_bf16(ahH[kk], B10, ahn, 0, 0, 0);
      ahn = __builtin_amdgcn_mfma_f32_16x16x32_bf16(ahH[kk], B11, ahn, 0, 0, 0);
      ahn = __builtin_amdgcn_mfma_f32_16x16x32_bf16(ahL[kk], B10, ahn, 0, 0, 0);
    }
    int col = c0g + ar;
    float bir = b_ih[col], biz = b_ih[128 + col], bin = b_ih[256 + col];
    float bhr = b_hh[col], bhz = b_hh[128 + col], bhn = b_hh[256 + col];
#pragma unroll
    for (int j = 0; j < 4; ++j) {
      int row = node0 + hi * 4 + j;
      int idx = row * 128 + col;
      float gr = air[j] + bir + ahr[j] + bhr;
      float gz = aiz[j] + biz + ahz[j] + bhz;
      float r  = 1.f / (1.f + expf(-gr));
      float zg = 1.f / (1.f + expf(-gz));
      float nn = tanhf(ain[j] + bin + r * (ahn[j] + bhn));
      float hp = b2f(hH[idx]) + b2f(hL[idx]);   // own (row,col): no race
      float hn = (1.f - zg) * nn + zg * hp;
      ushort_t hib = f2b(hn);
      hH[idx] = hib;
      hL[idx] = f2b(hn - b2f(hib));
    }
  }
}

// ---------------- heads (h from hi/lo planes) -------------------------------
__global__ __launch_bounds__(256) void k_musig(const ushort_t* __restrict__ hH,
                                               const ushort_t* __restrict__ hL,
                                               const float* __restrict__ w1,
                                               const float* __restrict__ b1,
                                               const float* __restrict__ w2,
                                               const float* __restrict__ b2,
                                               float* __restrict__ mu,
                                               float* __restrict__ sigma) {
  int t = threadIdx.x;
  int lane = t & 63, wv = t >> 6;
  int n = blockIdx.x * 4 + wv;
  uint32_t vh = *(const uint32_t*)&hH[n * 128 + lane * 2];
  uint32_t vl = *(const uint32_t*)&hL[n * 128 + lane * 2];
  float hx = b2f(vh & 0xFFFFu) + b2f(vl & 0xFFFFu);
  float hy = b2f(vh >> 16) + b2f(vl >> 16);
  hx = fmaxf(hx, 0.f); hy = fmaxf(hy, 0.f);
  float2 w1v = *(const float2*)&w1[lane * 2];
  float2 w2v = *(const float2*)&w2[lane * 2];
  float a = hx * w1v.x + hy * w1v.y;
  float b = hx * w2v.x + hy * w2v.y;
#pragma unroll
  for (int off = 32; off > 0; off >>= 1) {
    a += __shfl_down(a, off);
    b += __shfl_down(b, off);
  }
  if (lane == 0) {
    mu[n] = a + b1[0];
    float v = b + b2[0];
    sigma[n] = fmaxf(v, 0.f) + log1pf(expf(-fabsf(v)));
  }
}

// ---------------- sampler (fp64 internal): analytic Cholesky ----------------
__device__ __forceinline__ double dscan_incl(double v, volatile double* buf, int i,
                                             double* tot) {
  buf[i] = v;
  __syncthreads();
#pragma unroll
  for (int off = 1; off < 256; off <<= 1) {
    double add = (i >= off) ? buf[i - off] : 0.0;
    __syncthreads();
    buf[i] += add;
    __syncthreads();
  }
  double incl = buf[i];
  *tot = buf[255];
  __syncthreads();
  return incl;
}

__global__ __launch_bounds__(256) void k_sample(const float* __restrict__ mu,
                                                const float* __restrict__ sigma,
                                                const float* __restrict__ zbuf,
                                                float* __restrict__ out) {
  __shared__ double buf[256];
  __shared__ double lastd[2];
  int g = blockIdx.x, i = threadIdx.x;
  int n = (g << 8) + i;
  double sig = (double)sigma[n], muv = (double)mu[n];
  bool isLast = (i == 255);
  if (isLast) { lastd[0] = sig; lastd[1] = muv; }
  double s   = isLast ? 0.0 : sig;
  double mui = isLast ? 0.0 : muv;
  double tS, tM, tY, tX;
  double inclS = dscan_incl(s, buf, i, &tS);
  dscan_incl(mui, buf, i, &tM);
  double sigLast = lastd[0], muLast = lastd[1];
  double denom = tS + sigLast;
  double c = -muLast / sigLast;
  double pre = inclS - s;
  double suffix  = denom - pre;
  double suffix1 = suffix - s;
  double sigL = isLast ? 0.0 : sqrt(s * suffix1 / suffix);
  double cL   = isLast ? 0.0 : (-s / (suffix * sigL));
  double zv   = isLast ? 0.0 : (double)zbuf[g * 255 + i];
  double y = cL * zv;
  double inclY = dscan_incl(y, buf, i, &tY);
  double Pz = inclY - y;
  double rm = s * c + mui - s * (c * tS + tM) / denom;
  double X = rm + s * Pz + sigL * zv;
  if (isLast) X = 0.0;
  dscan_incl(X, buf, i, &tX);
  out[n] = (float)(isLast ? (0.0 - tX) : X);
}

// ---------------------------------------------------------------------------
extern "C" void kernel_launch(void* const* d_in, const int* in_sizes, int n_in,
                              void* d_out, int out_size, void* d_ws, size_t ws_size,
                              hipStream_t stream) {
  const float* x      = (const float*)d_in[0];
  const float* lin0_w = (const float*)d_in[1];
  const float* ggc_w  = (const float*)d_in[2];
  const float* w_ih   = (const float*)d_in[3];
  const float* w_hh   = (const float*)d_in[4];
  const float* b_ih   = (const float*)d_in[5];
  const float* b_hh   = (const float*)d_in[6];
  const float* lin1_w = (const float*)d_in[7];
  const float* lin1_b = (const float*)d_in[8];
  const float* lin2_w = (const float*)d_in[9];
  const float* lin2_b = (const float*)d_in[10];
  const int*   ei     = (const int*)d_in[11];
  float* out = (float*)d_out;

  char* ws = (char*)d_ws;
  float*    m      = (float*)   (ws + 0);          // 16 MB
  ushort_t* hbH    = (ushort_t*)(ws + 16777216);   // 8 MB
  ushort_t* hbL    = (ushort_t*)(ws + 25165824);   // 8 MB
  ushort_t* mgH    = (ushort_t*)(ws + 33554432);   // 8 MB
  ushort_t* mgL    = (ushort_t*)(ws + 41943040);   // 8 MB
  ushort_t* wihH   = (ushort_t*)(ws + 50331648);   // 96 KB
  ushort_t* wihL   = (ushort_t*)(ws + 50429952);   // 96 KB
  ushort_t* whhH   = (ushort_t*)(ws + 50528256);   // 96 KB
  ushort_t* whhL   = (ushort_t*)(ws + 50626560);   // 96 KB
  ushort_t* GH     = (ushort_t*)(ws + 50724864);   // 128 KB [mu aliases]
  ushort_t* GL     = (ushort_t*)(ws + 50855936);   // 128 KB
  float*    zbuf   = (float*)   (ws + 50987008);   // 128 KB [counts aliases]
  float*    sigma  = (float*)   (ws + 51118080);   // 128 KB
  int*      row_ptr= (int*)     (ws + 51249152);   // 128.5 KB slot
  int*      srcs   = (int*)     (ws + 51380736);   // 2 MB
  float*    mu     = (float*)GH;                   // alias: k_musig after all k_mm
  int*      counts = (int*)zbuf;                   // alias: CSR build before k_zgen
  const size_t WS_NEEDED = 53477888;               // proven available
  if (ws_size < WS_NEEDED) return;

  // CSR build (counts aliases zbuf; done before k_zgen)
  k_zero<<<32, 256, 0, stream>>>(counts, N_NODES);
  k_hist<<<1024, 256, 0, stream>>>(ei, counts);
  k_scan<<<1, 1024, 0, stream>>>(counts, row_ptr);
  k_zero<<<32, 256, 0, stream>>>(counts, N_NODES);
  k_fill<<<1024, 256, 0, stream>>>(ei, row_ptr, counts, srcs);

  k_wprep<<<192, 256, 0, stream>>>(w_ih, w_hh, wihH, wihL, whhH, whhL);
  k_gprep<<<256, 256, 0, stream>>>(ggc_w, GH, GL);
  k_zgen<<<128, 256, 0, stream>>>(zbuf);
  k_lin0<<<8192, 256, 0, stream>>>(x, lin0_w, hbH, hbL);

  for (int L = 0; L < 4; ++L) {
    k_mm_mfma<<<512, 256, 0, stream>>>(hbH, hbL, GH + (size_t)L * 16384,
                                       GL + (size_t)L * 16384, m);
    k_agg<<<8192, 256, 0, stream>>>(m, mgH, mgL, row_ptr, srcs);
    k_gru_mfma<<<512, 256, 0, stream>>>(mgH, mgL, hbH, hbL,
                                        wihH, wihL, whhH, whhL, b_ih, b_hh);
  }

  k_musig<<<8192, 256, 0, stream>>>(hbH, hbL, lin1_w, lin1_b, lin2_w, lin2_b,
                                    mu, sigma);
  k_sample<<<128, 256, 0, stream>>>(mu, sigma, zbuf, out);
}

// Round 9
// 507.023 us; speedup vs baseline: 2.1394x; 1.1796x over previous
//
#include <hip/hip_runtime.h>
#include <stdint.h>

#define N_NODES 32768
#define N_EDGES 524288
#define NODE_MASK (N_NODES - 1)

typedef __attribute__((ext_vector_type(8))) short bf16x8;
typedef __attribute__((ext_vector_type(4))) float f32x4;
typedef unsigned short ushort_t;

__device__ __forceinline__ ushort_t f2b(float f) {  // f32 -> bf16 RNE
  uint32_t u = __float_as_uint(f);
  return (ushort_t)((u + 0x7FFFu + ((u >> 16) & 1u)) >> 16);
}
__device__ __forceinline__ float b2f(uint32_t lo16) {
  return __uint_as_float(lo16 << 16);
}

// split f32[8] -> (hi trunc, lo RNE) bf16x8 planes
__device__ __forceinline__ void split8(const float* __restrict__ p,
                                       bf16x8* H, bf16x8* L) {
  bf16x8 h, lo;
#pragma unroll
  for (int i = 0; i < 8; ++i) {
    float x = p[i];
    uint32_t u = __float_as_uint(x);
    ushort_t hb = (ushort_t)(u >> 16);                 // truncation split
    float r = x - __uint_as_float((uint32_t)hb << 16); // exact residual
    h[i] = (short)hb;
    lo[i] = (short)f2b(r);
  }
  *H = h; *L = lo;
}

// ---------------- threefry2x32 (Threefry-20, partitionable mode) ------------
__device__ __forceinline__ uint32_t rotl32(uint32_t v, int r) {
  return (v << r) | (v >> (32 - r));
}

__device__ __forceinline__ void threefry2x32(uint32_t k0, uint32_t k1,
                                             uint32_t x0, uint32_t x1,
                                             uint32_t* o0, uint32_t* o1) {
  uint32_t k2 = k0 ^ k1 ^ 0x1BD11BDAu;
  x0 += k0; x1 += k1;
  x0 += x1; x1 = rotl32(x1, 13); x1 ^= x0;
  x0 += x1; x1 = rotl32(x1, 15); x1 ^= x0;
  x0 += x1; x1 = rotl32(x1, 26); x1 ^= x0;
  x0 += x1; x1 = rotl32(x1,  6); x1 ^= x0;
  x0 += k1; x1 += k2 + 1u;
  x0 += x1; x1 = rotl32(x1, 17); x1 ^= x0;
  x0 += x1; x1 = rotl32(x1, 29); x1 ^= x0;
  x0 += x1; x1 = rotl32(x1, 16); x1 ^= x0;
  x0 += x1; x1 = rotl32(x1, 24); x1 ^= x0;
  x0 += k2; x1 += k0 + 2u;
  x0 += x1; x1 = rotl32(x1, 13); x1 ^= x0;
  x0 += x1; x1 = rotl32(x1, 15); x1 ^= x0;
  x0 += x1; x1 = rotl32(x1, 26); x1 ^= x0;
  x0 += x1; x1 = rotl32(x1,  6); x1 ^= x0;
  x0 += k0; x1 += k1 + 3u;
  x0 += x1; x1 = rotl32(x1, 17); x1 ^= x0;
  x0 += x1; x1 = rotl32(x1, 29); x1 ^= x0;
  x0 += x1; x1 = rotl32(x1, 16); x1 ^= x0;
  x0 += x1; x1 = rotl32(x1, 24); x1 ^= x0;
  x0 += k1; x1 += k2 + 4u;
  x0 += x1; x1 = rotl32(x1, 13); x1 ^= x0;
  x0 += x1; x1 = rotl32(x1, 15); x1 ^= x0;
  x0 += x1; x1 = rotl32(x1, 26); x1 ^= x0;
  x0 += x1; x1 = rotl32(x1,  6); x1 ^= x0;
  x0 += k2; x1 += k0 + 5u;
  *o0 = x0; *o1 = x1;
}

__device__ __forceinline__ float bits_to_normal(uint32_t b) {
  uint32_t fb = (b >> 9) | 0x3F800000u;
  float f = __uint_as_float(fb) - 1.0f;          // [0,1)
  const float LO = -0.99999994f;
  float u = f * 2.0f + LO;
  u = fmaxf(LO, u);
  double zd = 1.4142135623730951 * erfinv((double)u);
  return (float)zd;
}

__global__ void k_zgen(float* __restrict__ z) {
  int i = blockIdx.x * blockDim.x + threadIdx.x;
  if (i >= 32640) return;
  uint32_t o0, o1;
  threefry2x32(0u, 123u, 0u, (uint32_t)i, &o0, &o1);
  z[i] = bits_to_normal(o0 ^ o1);
}

// ---------------- zero helper ------------------------------------------------
__global__ void k_zero(int* __restrict__ p, int n) {
  for (int i = blockIdx.x * blockDim.x + threadIdx.x; i < n;
       i += gridDim.x * blockDim.x)
    p[i] = 0;
}

// ---------------- CSR build (edge_index int32) ------------------------------
__global__ void k_hist(const int* __restrict__ ei, int* __restrict__ counts) {
  for (int e = blockIdx.x * blockDim.x + threadIdx.x; e < N_EDGES;
       e += gridDim.x * blockDim.x)
    atomicAdd(&counts[ei[N_EDGES + e] & NODE_MASK], 1);
}

__global__ __launch_bounds__(1024) void k_scan(const int* __restrict__ counts,
                                               int* __restrict__ row_ptr) {
  __shared__ int part[1024];
  int t = threadIdx.x;
  const int CH = N_NODES / 1024;  // 32
  int base = t * CH;
  int s = 0;
  for (int i = 0; i < CH; ++i) s += counts[base + i];
  part[t] = s;
  __syncthreads();
  for (int off = 1; off < 1024; off <<= 1) {
    int add = (t >= off) ? part[t - off] : 0;
    __syncthreads();
    part[t] += add;
    __syncthreads();
  }
  int run = (t == 0) ? 0 : part[t - 1];
  for (int i = 0; i < CH; ++i) { row_ptr[base + i] = run; run += counts[base + i]; }
  if (t == 1023) row_ptr[N_NODES] = run;
}

__global__ void k_fill(const int* __restrict__ ei, const int* __restrict__ row_ptr,
                       int* __restrict__ cursor, int* __restrict__ srcs) {
  for (int e = blockIdx.x * blockDim.x + threadIdx.x; e < N_EDGES;
       e += gridDim.x * blockDim.x) {
    int d = ei[N_EDGES + e] & NODE_MASK;
    int pos = row_ptr[d] + atomicAdd(&cursor[d], 1);
    srcs[pos] = ei[e] & NODE_MASK;
  }
}

// ---------------- weight prep: f32 -> (hi,lo) bf16 planes, [384][128] -------
__global__ void k_wprep(const float* __restrict__ w_ih, const float* __restrict__ w_hh,
                        ushort_t* __restrict__ wihH, ushort_t* __restrict__ wihL,
                        ushort_t* __restrict__ whhH, ushort_t* __restrict__ whhL) {
  int i = blockIdx.x * 256 + threadIdx.x;
  if (i >= 384 * 128) return;
  float a = w_ih[i];
  ushort_t ah = f2b(a);
  wihH[i] = ah; wihL[i] = f2b(a - b2f(ah));
  float b = w_hh[i];
  ushort_t bh = f2b(b);
  whhH[i] = bh; whhL[i] = f2b(b - b2f(bh));
}

// ---------------- G prep: GT[L][c][k] hi/lo planes from ggc_w[L][k][c] ------
__global__ void k_gprep(const float* __restrict__ G,
                        ushort_t* __restrict__ GH, ushort_t* __restrict__ GL) {
  int i = blockIdx.x * 256 + threadIdx.x;
  if (i >= 4 * 128 * 128) return;
  int L = i >> 14, j = i & 16383;
  int c = j >> 7, k = j & 127;
  float g = G[L * 16384 + k * 128 + c];
  ushort_t gh = f2b(g);
  GH[i] = gh; GL[i] = f2b(g - b2f(gh));
}

// ---------------- lin0: hf = sigmoid(x @ lin0_w.T), padded to 128 (f32) -----
__global__ __launch_bounds__(256) void k_lin0(const float* __restrict__ x,
                                              const float* __restrict__ w,
                                              float* __restrict__ hf) {
  __shared__ float sw[64][33];
  __shared__ float sx[4][32];
  int t = threadIdx.x;
  for (int e = t; e < 64 * 32; e += 256) sw[e >> 5][e & 31] = w[e];
  int node0 = blockIdx.x * 4;
  if (t < 128) sx[t >> 5][t & 31] = x[node0 * 32 + t];
  __syncthreads();
  int c = t & 63, nl = t >> 6;
  float acc = 0.f;
#pragma unroll
  for (int k = 0; k < 32; ++k) acc += sx[nl][k] * sw[c][k];
  float s = 1.f / (1.f + expf(-acc));
  int n = node0 + nl;
  hf[n * 128 + c] = s;
  hf[n * 128 + 64 + c] = 0.f;
}

// ---------------- m = h @ G via 3-term split MFMA; LDS-staged swizzled G ----
__global__ __launch_bounds__(256) void k_mm_mfma(const float* __restrict__ hf,
                                                 const ushort_t* __restrict__ GH,
                                                 const ushort_t* __restrict__ GL,
                                                 float* __restrict__ m) {
  __shared__ float4 glds4[4096];  // 64 KB: [plane 2][row 128][256 B swizzled]
  int t = threadIdx.x;
  int w = t >> 6, l = t & 63;
  int node0 = blockIdx.x * 64 + w * 16;
  int ar = l & 15, hi = l >> 4, ak = hi * 8;
  bf16x8 aH[4], aL[4];
#pragma unroll
  for (int kk = 0; kk < 4; ++kk)
    split8(&hf[(node0 + ar) * 128 + kk * 32 + ak], &aH[kk], &aL[kk]);
  // stage G (hi+lo) into LDS, row-XOR-swizzled (16B granules)
#pragma unroll
  for (int i = t; i < 4096; i += 256) {
    int p = i >> 11, chunk = i & 2047;
    const ushort_t* base = p ? GL : GH;
    float4 v = *(const float4*)(base + chunk * 8);
    int row = chunk >> 4, c16 = chunk & 15;
    int byte = p * 32768 + row * 256 + ((c16 * 16) ^ ((row & 7) << 4));
    *(float4*)((char*)glds4 + byte) = v;
  }
  __syncthreads();
  const char* lds = (const char*)glds4;
#pragma unroll
  for (int nt = 0; nt < 8; ++nt) {
    f32x4 acc = {0.f, 0.f, 0.f, 0.f};
    int row = nt * 16 + ar;
    int rbase = row * 256;
    int rsw = (row & 7) << 4;
#pragma unroll
    for (int kk = 0; kk < 4; ++kk) {
      int bin = (kk * 64 + hi * 16) ^ rsw;
      bf16x8 bH = *(const bf16x8*)(lds + rbase + bin);
      bf16x8 bL = *(const bf16x8*)(lds + 32768 + rbase + bin);
      acc = __builtin_amdgcn_mfma_f32_16x16x32_bf16(aH[kk], bH, acc, 0, 0, 0);
      acc = __builtin_amdgcn_mfma_f32_16x16x32_bf16(aH[kk], bL, acc, 0, 0, 0);
      acc = __builtin_amdgcn_mfma_f32_16x16x32_bf16(aL[kk], bH, acc, 0, 0, 0);
    }
    int col = nt * 16 + ar;
#pragma unroll
    for (int j = 0; j < 4; ++j) {
      int orow = hi * 4 + j;
      m[(node0 + orow) * 128 + col] = acc[j];
    }
  }
}

// ---------------- segment-sum gather: f32 in, hi/lo planes out --------------
__global__ void k_agg(const float* __restrict__ m,
                      ushort_t* __restrict__ mgH, ushort_t* __restrict__ mgL,
                      const int* __restrict__ row_ptr, const int* __restrict__ srcs) {
  int wid = (blockIdx.x * blockDim.x + threadIdx.x) >> 6;
  int lane = threadIdx.x & 63;
  if (wid >= N_NODES) return;
  int beg = row_ptr[wid], end = row_ptr[wid + 1];
  float ax = 0.f, ay = 0.f;
  for (int e = beg; e < end; ++e) {
    int s = srcs[e] & NODE_MASK;
    float2 v = *(const float2*)&m[s * 128 + lane * 2];
    ax += v.x; ay += v.y;
  }
  ushort_t xh = f2b(ax), yh = f2b(ay);
  ushort_t xl = f2b(ax - b2f(xh)), yl = f2b(ay - b2f(yh));
  *(uint32_t*)&mgH[wid * 128 + lane * 2] = (uint32_t)xh | ((uint32_t)yh << 16);
  *(uint32_t*)&mgL[wid * 128 + lane * 2] = (uint32_t)xl | ((uint32_t)yl << 16);
}

// ---------------- fused GRU via 3-term split MFMA ---------------------------
// Weights staged per ct via global_load_lds (linear LDS dest, pre-swizzled
// global source; read side applies the same XOR involution). h kept f32.
__global__ __launch_bounds__(256, 2) void k_gru_mfma(
    const ushort_t* __restrict__ mgH, const ushort_t* __restrict__ mgL,
    float* __restrict__ hf,
    const ushort_t* __restrict__ wihH, const ushort_t* __restrict__ wihL,
    const ushort_t* __restrict__ whhH, const ushort_t* __restrict__ whhL,
    const float* __restrict__ b_ih, const float* __restrict__ b_hh) {
  __shared__ __align__(16) char smem[49152];  // 12 slices x 4 KB
  int t = threadIdx.x;
  int w = t >> 6, l = t & 63;
  int node0 = blockIdx.x * 64 + w * 16;
  int ar = l & 15, hi = l >> 4, ak = hi * 8;
  bf16x8 amH[4], amL[4], ahH[4], ahL[4];
#pragma unroll
  for (int kk = 0; kk < 4; ++kk) {
    int o = (node0 + ar) * 128 + kk * 32 + ak;
    amH[kk] = *(const bf16x8*)&mgH[o];
    amL[kk] = *(const bf16x8*)&mgL[o];
    split8(&hf[o], &ahH[kk], &ahL[kk]);
  }
  // per-lane pre-swizzled global source pointers (12 x 1KB wave chunks / ct)
  const ushort_t* pq[12];
#pragma unroll
  for (int q = 0; q < 12; ++q) {
    int i = (q * 4 + w) * 64 + l;          // linear granule index in 48 KB
    int s = i >> 8, r = (i >> 4) & 15, gl = i & 15;
    int gsrc = gl ^ (r & 7);               // inverse of read-side XOR
    int mtx = s / 6, rem = s % 6, gate = rem >> 1, plane = rem & 1;
    const ushort_t* base = mtx ? (plane ? whhL : whhH) : (plane ? wihL : wihH);
    pq[q] = base + (gate * 128 + r) * 128 + gsrc * 8;
  }
  const char* lds = (const char*)smem;
  for (int ct = 0; ct < 8; ++ct) {
    int c0 = ct * 16;
    // async stage this ct's 48 KB of weights
#pragma unroll
    for (int q = 0; q < 12; ++q) {
      __builtin_amdgcn_global_load_lds(
          (const __attribute__((address_space(1))) void*)(pq[q] + c0 * 128),
          (__attribute__((address_space(3))) void*)(smem + (q * 4 + w) * 1024),
          16, 0, 0);
    }
    // prefetch previous-h (coalesced f32; own nodes/cols only)
    int col = c0 + ar;
    float hp[4];
#pragma unroll
    for (int j = 0; j < 4; ++j)
      hp[j] = hf[(node0 + hi * 4 + j) * 128 + col];
    __syncthreads();  // staging landed (compiler drains vmcnt before barrier)
    f32x4 air = {0.f,0.f,0.f,0.f}, aiz = air, ain = air;
    f32x4 ahr = air, ahz = air, ahn = air;
    int rbase = ar * 256;
    int rsw = (ar & 7) << 4;
#pragma unroll
    for (int kk = 0; kk < 4; ++kk) {
      int bin = rbase + ((kk * 64 + hi * 16) ^ rsw);
      bf16x8 B0  = *(const bf16x8*)(lds + 0 * 4096 + bin);
      bf16x8 B1  = *(const bf16x8*)(lds + 1 * 4096 + bin);
      bf16x8 B2  = *(const bf16x8*)(lds + 2 * 4096 + bin);
      bf16x8 B3  = *(const bf16x8*)(lds + 3 * 4096 + bin);
      bf16x8 B4  = *(const bf16x8*)(lds + 4 * 4096 + bin);
      bf16x8 B5  = *(const bf16x8*)(lds + 5 * 4096 + bin);
      bf16x8 B6  = *(const bf16x8*)(lds + 6 * 4096 + bin);
      bf16x8 B7  = *(const bf16x8*)(lds + 7 * 4096 + bin);
      bf16x8 B8  = *(const bf16x8*)(lds + 8 * 4096 + bin);
      bf16x8 B9  = *(const bf16x8*)(lds + 9 * 4096 + bin);
      bf16x8 B10 = *(const bf16x8*)(lds + 10 * 4096 + bin);
      bf16x8 B11 = *(const bf16x8*)(lds + 11 * 4096 + bin);
      air = __builtin_amdgcn_mfma_f32_16x16x32_bf16(amH[kk], B0,  air, 0, 0, 0);
      air = __builtin_amdgcn_mfma_f32_16x16x32_bf16(amH[kk], B1,  air, 0, 0, 0);
      air = __builtin_amdgcn_mfma_f32_16x16x32_bf16(amL[kk], B0,  air, 0, 0, 0);
      aiz = __builtin_amdgcn_mfma_f32_16x16x32_bf16(amH[kk], B2,  aiz, 0, 0, 0);
      aiz = __builtin_amdgcn_mfma_f32_16x16x32_bf16(amH[kk], B3,  aiz, 0, 0, 0);
      aiz = __builtin_amdgcn_mfma_f32_16x16x32_bf16(amL[kk], B2,  aiz, 0, 0, 0);
      ain = __builtin_amdgcn_mfma_f32_16x16x32_bf16(amH[kk], B4,  ain, 0, 0, 0);
      ain = __builtin_amdgcn_mfma_f32_16x16x32_bf16(amH[kk], B5,  ain, 0, 0, 0);
      ain = __builtin_amdgcn_mfma_f32_16x16x32_bf16(amL[kk], B4,  ain, 0, 0, 0);
      ahr = __builtin_amdgcn_mfma_f32_16x16x32_bf16(ahH[kk], B6,  ahr, 0, 0, 0);
      ahr = __builtin_amdgcn_mfma_f32_16x16x32_bf16(ahH[kk], B7,  ahr, 0, 0, 0);
      ahr = __builtin_amdgcn_mfma_f32_16x16x32_bf16(ahL[kk], B6,  ahr, 0, 0, 0);
      ahz = __builtin_amdgcn_mfma_f32_16x16x32_bf16(ahH[kk], B8,  ahz, 0, 0, 0);
      ahz = __builtin_amdgcn_mfma_f32_16x16x32_bf16(ahH[kk], B9,  ahz, 0, 0, 0);
      ahz = __builtin_amdgcn_mfma_f32_16x16x32_bf16(ahL[kk], B8,  ahz, 0, 0, 0);
      ahn = __builtin_amdgcn_mfma_f32_16x16x32_bf16(ahH[kk], B10, ahn, 0, 0, 0);
      ahn = __builtin_amdgcn_mfma_f32_16x16x32_bf16(ahH[kk], B11, ahn, 0, 0, 0);
      ahn = __builtin_amdgcn_mfma_f32_16x16x32_bf16(ahL[kk], B10, ahn, 0, 0, 0);
    }
    float bir = b_ih[col], biz = b_ih[128 + col], bin = b_ih[256 + col];
    float bhr = b_hh[col], bhz = b_hh[128 + col], bhn = b_hh[256 + col];
#pragma unroll
    for (int j = 0; j < 4; ++j) {
      int idx = (node0 + hi * 4 + j) * 128 + col;
      float gr = air[j] + bir + ahr[j] + bhr;
      float gz = aiz[j] + biz + ahz[j] + bhz;
      float r  = 1.f / (1.f + expf(-gr));
      float zg = 1.f / (1.f + expf(-gz));
      float nn = tanhf(ain[j] + bin + r * (ahn[j] + bhn));
      hf[idx] = (1.f - zg) * nn + zg * hp[j];
    }
    __syncthreads();  // all LDS reads done before next ct restages
  }
}

// ---------------- heads (f32 hf) ---------------------------------------------
__global__ __launch_bounds__(256) void k_musig(const float* __restrict__ hf,
                                               const float* __restrict__ w1,
                                               const float* __restrict__ b1,
                                               const float* __restrict__ w2,
                                               const float* __restrict__ b2,
                                               float* __restrict__ mu,
                                               float* __restrict__ sigma) {
  int t = threadIdx.x;
  int lane = t & 63, wv = t >> 6;
  int n = blockIdx.x * 4 + wv;
  float2 hv = *(const float2*)&hf[n * 128 + lane * 2];
  hv.x = fmaxf(hv.x, 0.f); hv.y = fmaxf(hv.y, 0.f);
  float2 w1v = *(const float2*)&w1[lane * 2];
  float2 w2v = *(const float2*)&w2[lane * 2];
  float a = hv.x * w1v.x + hv.y * w1v.y;
  float b = hv.x * w2v.x + hv.y * w2v.y;
#pragma unroll
  for (int off = 32; off > 0; off >>= 1) {
    a += __shfl_down(a, off);
    b += __shfl_down(b, off);
  }
  if (lane == 0) {
    mu[n] = a + b1[0];
    float v = b + b2[0];
    sigma[n] = fmaxf(v, 0.f) + log1pf(expf(-fabsf(v)));
  }
}

// ---------------- sampler (fp64 internal): analytic Cholesky ----------------
__device__ __forceinline__ double dscan_incl(double v, volatile double* buf, int i,
                                             double* tot) {
  buf[i] = v;
  __syncthreads();
#pragma unroll
  for (int off = 1; off < 256; off <<= 1) {
    double add = (i >= off) ? buf[i - off] : 0.0;
    __syncthreads();
    buf[i] += add;
    __syncthreads();
  }
  double incl = buf[i];
  *tot = buf[255];
  __syncthreads();
  return incl;
}

__global__ __launch_bounds__(256) void k_sample(const float* __restrict__ mu,
                                                const float* __restrict__ sigma,
                                                const float* __restrict__ zbuf,
                                                float* __restrict__ out) {
  __shared__ double buf[256];
  __shared__ double lastd[2];
  int g = blockIdx.x, i = threadIdx.x;
  int n = (g << 8) + i;
  double sig = (double)sigma[n], muv = (double)mu[n];
  bool isLast = (i == 255);
  if (isLast) { lastd[0] = sig; lastd[1] = muv; }
  double s   = isLast ? 0.0 : sig;
  double mui = isLast ? 0.0 : muv;
  double tS, tM, tY, tX;
  double inclS = dscan_incl(s, buf, i, &tS);
  dscan_incl(mui, buf, i, &tM);
  double sigLast = lastd[0], muLast = lastd[1];
  double denom = tS + sigLast;
  double c = -muLast / sigLast;
  double pre = inclS - s;
  double suffix  = denom - pre;
  double suffix1 = suffix - s;
  double sigL = isLast ? 0.0 : sqrt(s * suffix1 / suffix);
  double cL   = isLast ? 0.0 : (-s / (suffix * sigL));
  double zv   = isLast ? 0.0 : (double)zbuf[g * 255 + i];
  double y = cL * zv;
  double inclY = dscan_incl(y, buf, i, &tY);
  double Pz = inclY - y;
  double rm = s * c + mui - s * (c * tS + tM) / denom;
  double X = rm + s * Pz + sigL * zv;
  if (isLast) X = 0.0;
  dscan_incl(X, buf, i, &tX);
  out[n] = (float)(isLast ? (0.0 - tX) : X);
}

// ---------------------------------------------------------------------------
extern "C" void kernel_launch(void* const* d_in, const int* in_sizes, int n_in,
                              void* d_out, int out_size, void* d_ws, size_t ws_size,
                              hipStream_t stream) {
  const float* x      = (const float*)d_in[0];
  const float* lin0_w = (const float*)d_in[1];
  const float* ggc_w  = (const float*)d_in[2];
  const float* w_ih   = (const float*)d_in[3];
  const float* w_hh   = (const float*)d_in[4];
  const float* b_ih   = (const float*)d_in[5];
  const float* b_hh   = (const float*)d_in[6];
  const float* lin1_w = (const float*)d_in[7];
  const float* lin1_b = (const float*)d_in[8];
  const float* lin2_w = (const float*)d_in[9];
  const float* lin2_b = (const float*)d_in[10];
  const int*   ei     = (const int*)d_in[11];
  float* out = (float*)d_out;

  char* ws = (char*)d_ws;
  float*    m      = (float*)   (ws + 0);          // 16 MB
  float*    hf     = (float*)   (ws + 16777216);   // 16 MB (f32 master h)
  ushort_t* mgH    = (ushort_t*)(ws + 33554432);   // 8 MB
  ushort_t* mgL    = (ushort_t*)(ws + 41943040);   // 8 MB
  ushort_t* wihH   = (ushort_t*)(ws + 50331648);   // 96 KB
  ushort_t* wihL   = (ushort_t*)(ws + 50429952);   // 96 KB
  ushort_t* whhH   = (ushort_t*)(ws + 50528256);   // 96 KB
  ushort_t* whhL   = (ushort_t*)(ws + 50626560);   // 96 KB
  ushort_t* GH     = (ushort_t*)(ws + 50724864);   // 128 KB [mu aliases]
  ushort_t* GL     = (ushort_t*)(ws + 50855936);   // 128 KB
  float*    zbuf   = (float*)   (ws + 50987008);   // 128 KB [counts aliases]
  float*    sigma  = (float*)   (ws + 51118080);   // 128 KB
  int*      row_ptr= (int*)     (ws + 51249152);   // 128.5 KB slot
  int*      srcs   = (int*)     (ws + 51380736);   // 2 MB
  float*    mu     = (float*)GH;                   // alias: used after all k_mm
  int*      counts = (int*)zbuf;                   // alias: CSR before k_zgen
  const size_t WS_NEEDED = 53477888;               // proven available
  if (ws_size < WS_NEEDED) return;

  // CSR build (counts aliases zbuf; done before k_zgen)
  k_zero<<<32, 256, 0, stream>>>(counts, N_NODES);
  k_hist<<<1024, 256, 0, stream>>>(ei, counts);
  k_scan<<<1, 1024, 0, stream>>>(counts, row_ptr);
  k_zero<<<32, 256, 0, stream>>>(counts, N_NODES);
  k_fill<<<1024, 256, 0, stream>>>(ei, row_ptr, counts, srcs);

  k_wprep<<<192, 256, 0, stream>>>(w_ih, w_hh, wihH, wihL, whhH, whhL);
  k_gprep<<<256, 256, 0, stream>>>(ggc_w, GH, GL);
  k_zgen<<<128, 256, 0, stream>>>(zbuf);
  k_lin0<<<8192, 256, 0, stream>>>(x, lin0_w, hf);

  for (int L = 0; L < 4; ++L) {
    k_mm_mfma<<<512, 256, 0, stream>>>(hf, GH + (size_t)L * 16384,
                                       GL + (size_t)L * 16384, m);
    k_agg<<<8192, 256, 0, stream>>>(m, mgH, mgL, row_ptr, srcs);
    k_gru_mfma<<<512, 256, 0, stream>>>(mgH, mgL, hf,
                                        wihH, wihL, whhH, whhL, b_ih, b_hh);
  }

  k_musig<<<8192, 256, 0, stream>>>(hf, lin1_w, lin1_b, lin2_w, lin2_b, mu, sigma);
  k_sample<<<128, 256, 0, stream>>>(mu, sigma, zbuf, out);
}

// Round 10
// 406.568 us; speedup vs baseline: 2.6679x; 1.2471x over previous
//
#include <hip/hip_runtime.h>
#include <stdint.h>

#define N_NODES 32768
#define N_EDGES 524288
#define NODE_MASK (N_NODES - 1)

typedef __attribute__((ext_vector_type(8))) short bf16x8;
typedef __attribute__((ext_vector_type(4))) float f32x4;
typedef __attribute__((ext_vector_type(2))) _Float16 f16x2;
typedef unsigned short ushort_t;

__device__ __forceinline__ ushort_t f2b(float f) {  // f32 -> bf16 RNE
  uint32_t u = __float_as_uint(f);
  return (ushort_t)((u + 0x7FFFu + ((u >> 16) & 1u)) >> 16);
}
__device__ __forceinline__ float b2f(uint32_t lo16) {
  return __uint_as_float(lo16 << 16);
}

// split f32[8] -> (hi trunc, lo RNE) bf16x8 planes
__device__ __forceinline__ void split8(const float* __restrict__ p,
                                       bf16x8* H, bf16x8* L) {
  bf16x8 h, lo;
#pragma unroll
  for (int i = 0; i < 8; ++i) {
    float x = p[i];
    uint32_t u = __float_as_uint(x);
    ushort_t hb = (ushort_t)(u >> 16);                 // truncation split
    float r = x - __uint_as_float((uint32_t)hb << 16); // exact residual
    h[i] = (short)hb;
    lo[i] = (short)f2b(r);
  }
  *H = h; *L = lo;
}

// ---------------- threefry2x32 (Threefry-20, partitionable mode) ------------
__device__ __forceinline__ uint32_t rotl32(uint32_t v, int r) {
  return (v << r) | (v >> (32 - r));
}

__device__ __forceinline__ void threefry2x32(uint32_t k0, uint32_t k1,
                                             uint32_t x0, uint32_t x1,
                                             uint32_t* o0, uint32_t* o1) {
  uint32_t k2 = k0 ^ k1 ^ 0x1BD11BDAu;
  x0 += k0; x1 += k1;
  x0 += x1; x1 = rotl32(x1, 13); x1 ^= x0;
  x0 += x1; x1 = rotl32(x1, 15); x1 ^= x0;
  x0 += x1; x1 = rotl32(x1, 26); x1 ^= x0;
  x0 += x1; x1 = rotl32(x1,  6); x1 ^= x0;
  x0 += k1; x1 += k2 + 1u;
  x0 += x1; x1 = rotl32(x1, 17); x1 ^= x0;
  x0 += x1; x1 = rotl32(x1, 29); x1 ^= x0;
  x0 += x1; x1 = rotl32(x1, 16); x1 ^= x0;
  x0 += x1; x1 = rotl32(x1, 24); x1 ^= x0;
  x0 += k2; x1 += k0 + 2u;
  x0 += x1; x1 = rotl32(x1, 13); x1 ^= x0;
  x0 += x1; x1 = rotl32(x1, 15); x1 ^= x0;
  x0 += x1; x1 = rotl32(x1, 26); x1 ^= x0;
  x0 += x1; x1 = rotl32(x1,  6); x1 ^= x0;
  x0 += k0; x1 += k1 + 3u;
  x0 += x1; x1 = rotl32(x1, 17); x1 ^= x0;
  x0 += x1; x1 = rotl32(x1, 29); x1 ^= x0;
  x0 += x1; x1 = rotl32(x1, 16); x1 ^= x0;
  x0 += x1; x1 = rotl32(x1, 24); x1 ^= x0;
  x0 += k1; x1 += k2 + 4u;
  x0 += x1; x1 = rotl32(x1, 13); x1 ^= x0;
  x0 += x1; x1 = rotl32(x1, 15); x1 ^= x0;
  x0 += x1; x1 = rotl32(x1, 26); x1 ^= x0;
  x0 += x1; x1 = rotl32(x1,  6); x1 ^= x0;
  x0 += k2; x1 += k0 + 5u;
  *o0 = x0; *o1 = x1;
}

__device__ __forceinline__ float bits_to_normal(uint32_t b) {
  uint32_t fb = (b >> 9) | 0x3F800000u;
  float f = __uint_as_float(fb) - 1.0f;          // [0,1)
  const float LO = -0.99999994f;
  float u = f * 2.0f + LO;
  u = fmaxf(LO, u);
  double zd = 1.4142135623730951 * erfinv((double)u);
  return (float)zd;
}

__global__ void k_zgen(float* __restrict__ z) {
  int i = blockIdx.x * blockDim.x + threadIdx.x;
  if (i >= 32640) return;
  uint32_t o0, o1;
  threefry2x32(0u, 123u, 0u, (uint32_t)i, &o0, &o1);
  z[i] = bits_to_normal(o0 ^ o1);
}

// ---------------- zero helper ------------------------------------------------
__global__ void k_zero(int* __restrict__ p, int n) {
  for (int i = blockIdx.x * blockDim.x + threadIdx.x; i < n;
       i += gridDim.x * blockDim.x)
    p[i] = 0;
}

// ---------------- CSR build (edge_index int32) ------------------------------
__global__ void k_hist(const int* __restrict__ ei, int* __restrict__ counts) {
  for (int e = blockIdx.x * blockDim.x + threadIdx.x; e < N_EDGES;
       e += gridDim.x * blockDim.x)
    atomicAdd(&counts[ei[N_EDGES + e] & NODE_MASK], 1);
}

__global__ __launch_bounds__(1024) void k_scan(const int* __restrict__ counts,
                                               int* __restrict__ row_ptr) {
  __shared__ int part[1024];
  int t = threadIdx.x;
  const int CH = N_NODES / 1024;  // 32
  int base = t * CH;
  int s = 0;
  for (int i = 0; i < CH; ++i) s += counts[base + i];
  part[t] = s;
  __syncthreads();
  for (int off = 1; off < 1024; off <<= 1) {
    int add = (t >= off) ? part[t - off] : 0;
    __syncthreads();
    part[t] += add;
    __syncthreads();
  }
  int run = (t == 0) ? 0 : part[t - 1];
  for (int i = 0; i < CH; ++i) { row_ptr[base + i] = run; run += counts[base + i]; }
  if (t == 1023) row_ptr[N_NODES] = run;
}

__global__ void k_fill(const int* __restrict__ ei, const int* __restrict__ row_ptr,
                       int* __restrict__ cursor, int* __restrict__ srcs) {
  for (int e = blockIdx.x * blockDim.x + threadIdx.x; e < N_EDGES;
       e += gridDim.x * blockDim.x) {
    int d = ei[N_EDGES + e] & NODE_MASK;
    int pos = row_ptr[d] + atomicAdd(&cursor[d], 1);
    srcs[pos] = ei[e] & NODE_MASK;
  }
}

// ---------------- weight prep: f32 -> (hi,lo) bf16 planes, [384][128] -------
__global__ void k_wprep(const float* __restrict__ w_ih, const float* __restrict__ w_hh,
                        ushort_t* __restrict__ wihH, ushort_t* __restrict__ wihL,
                        ushort_t* __restrict__ whhH, ushort_t* __restrict__ whhL) {
  int i = blockIdx.x * 256 + threadIdx.x;
  if (i >= 384 * 128) return;
  float a = w_ih[i];
  ushort_t ah = f2b(a);
  wihH[i] = ah; wihL[i] = f2b(a - b2f(ah));
  float b = w_hh[i];
  ushort_t bh = f2b(b);
  whhH[i] = bh; whhL[i] = f2b(b - b2f(bh));
}

// ---------------- G prep: GT[L][c][k] hi/lo planes from ggc_w[L][k][c] ------
__global__ void k_gprep(const float* __restrict__ G,
                        ushort_t* __restrict__ GH, ushort_t* __restrict__ GL) {
  int i = blockIdx.x * 256 + threadIdx.x;
  if (i >= 4 * 128 * 128) return;
  int L = i >> 14, j = i & 16383;
  int c = j >> 7, k = j & 127;
  float g = G[L * 16384 + k * 128 + c];
  ushort_t gh = f2b(g);
  GH[i] = gh; GL[i] = f2b(g - b2f(gh));
}

// ---------------- lin0: hf = sigmoid(x @ lin0_w.T), padded to 128 (f32) -----
__global__ __launch_bounds__(256) void k_lin0(const float* __restrict__ x,
                                              const float* __restrict__ w,
                                              float* __restrict__ hf) {
  __shared__ float sw[64][33];
  __shared__ float sx[4][32];
  int t = threadIdx.x;
  for (int e = t; e < 64 * 32; e += 256) sw[e >> 5][e & 31] = w[e];
  int node0 = blockIdx.x * 4;
  if (t < 128) sx[t >> 5][t & 31] = x[node0 * 32 + t];
  __syncthreads();
  int c = t & 63, nl = t >> 6;
  float acc = 0.f;
#pragma unroll
  for (int k = 0; k < 32; ++k) acc += sx[nl][k] * sw[c][k];
  float s = 1.f / (1.f + expf(-acc));
  int n = node0 + nl;
  hf[n * 128 + c] = s;
  hf[n * 128 + 64 + c] = 0.f;
}

// ---------------- m = h @ G via 3-term split MFMA; f16 output ---------------
__global__ __launch_bounds__(256) void k_mm_mfma(const float* __restrict__ hf,
                                                 const ushort_t* __restrict__ GH,
                                                 const ushort_t* __restrict__ GL,
                                                 _Float16* __restrict__ m) {
  __shared__ float4 glds4[4096];  // 64 KB: [plane 2][row 128][256 B swizzled]
  int t = threadIdx.x;
  int w = t >> 6, l = t & 63;
  int node0 = blockIdx.x * 64 + w * 16;
  int ar = l & 15, hi = l >> 4, ak = hi * 8;
  bf16x8 aH[4], aL[4];
#pragma unroll
  for (int kk = 0; kk < 4; ++kk)
    split8(&hf[(node0 + ar) * 128 + kk * 32 + ak], &aH[kk], &aL[kk]);
  // stage G (hi+lo) into LDS, row-XOR-swizzled (16B granules)
#pragma unroll
  for (int i = t; i < 4096; i += 256) {
    int p = i >> 11, chunk = i & 2047;
    const ushort_t* base = p ? GL : GH;
    float4 v = *(const float4*)(base + chunk * 8);
    int row = chunk >> 4, c16 = chunk & 15;
    int byte = p * 32768 + row * 256 + ((c16 * 16) ^ ((row & 7) << 4));
    *(float4*)((char*)glds4 + byte) = v;
  }
  __syncthreads();
  const char* lds = (const char*)glds4;
#pragma unroll
  for (int nt = 0; nt < 8; ++nt) {
    f32x4 acc = {0.f, 0.f, 0.f, 0.f};
    int row = nt * 16 + ar;
    int rbase = row * 256;
    int rsw = (row & 7) << 4;
#pragma unroll
    for (int kk = 0; kk < 4; ++kk) {
      int bin = (kk * 64 + hi * 16) ^ rsw;
      bf16x8 bH = *(const bf16x8*)(lds + rbase + bin);
      bf16x8 bL = *(const bf16x8*)(lds + 32768 + rbase + bin);
      acc = __builtin_amdgcn_mfma_f32_16x16x32_bf16(aH[kk], bH, acc, 0, 0, 0);
      acc = __builtin_amdgcn_mfma_f32_16x16x32_bf16(aH[kk], bL, acc, 0, 0, 0);
      acc = __builtin_amdgcn_mfma_f32_16x16x32_bf16(aL[kk], bH, acc, 0, 0, 0);
    }
    int col = nt * 16 + ar;
#pragma unroll
    for (int j = 0; j < 4; ++j) {
      int orow = hi * 4 + j;
      m[(node0 + orow) * 128 + col] = (_Float16)acc[j];
    }
  }
}

// ---------------- segment-sum gather: f16 in, hi/lo bf16 planes out ---------
__global__ void k_agg(const _Float16* __restrict__ m,
                      ushort_t* __restrict__ mgH, ushort_t* __restrict__ mgL,
                      const int* __restrict__ row_ptr, const int* __restrict__ srcs) {
  int wid = (blockIdx.x * blockDim.x + threadIdx.x) >> 6;
  int lane = threadIdx.x & 63;
  if (wid >= N_NODES) return;
  int beg = row_ptr[wid], end = row_ptr[wid + 1];
  float ax = 0.f, ay = 0.f, bx = 0.f, by = 0.f;
  int e = beg;
  for (; e + 2 <= end; e += 2) {
    int s0 = srcs[e] & NODE_MASK;
    int s1 = srcs[e + 1] & NODE_MASK;
    f16x2 v0 = *(const f16x2*)&m[s0 * 128 + lane * 2];
    f16x2 v1 = *(const f16x2*)&m[s1 * 128 + lane * 2];
    ax += (float)v0[0]; ay += (float)v0[1];
    bx += (float)v1[0]; by += (float)v1[1];
  }
  if (e < end) {
    int s0 = srcs[e] & NODE_MASK;
    f16x2 v0 = *(const f16x2*)&m[s0 * 128 + lane * 2];
    ax += (float)v0[0]; ay += (float)v0[1];
  }
  ax += bx; ay += by;
  ushort_t xh = f2b(ax), yh = f2b(ay);
  ushort_t xl = f2b(ax - b2f(xh)), yl = f2b(ay - b2f(yh));
  *(uint32_t*)&mgH[wid * 128 + lane * 2] = (uint32_t)xh | ((uint32_t)yh << 16);
  *(uint32_t*)&mgL[wid * 128 + lane * 2] = (uint32_t)xl | ((uint32_t)yl << 16);
}

// ---------------- fused GRU via 3-term split MFMA ---------------------------
// Weights staged per ct via global_load_lds (linear LDS dest, pre-swizzled
// global source; read side applies the same XOR involution). h kept f32.
__global__ __launch_bounds__(256, 2) void k_gru_mfma(
    const ushort_t* __restrict__ mgH, const ushort_t* __restrict__ mgL,
    float* __restrict__ hf,
    const ushort_t* __restrict__ wihH, const ushort_t* __restrict__ wihL,
    const ushort_t* __restrict__ whhH, const ushort_t* __restrict__ whhL,
    const float* __restrict__ b_ih, const float* __restrict__ b_hh) {
  __shared__ __align__(16) char smem[49152];  // 12 slices x 4 KB
  int t = threadIdx.x;
  int w = t >> 6, l = t & 63;
  int node0 = blockIdx.x * 64 + w * 16;
  int ar = l & 15, hi = l >> 4, ak = hi * 8;
  bf16x8 amH[4], amL[4], ahH[4], ahL[4];
#pragma unroll
  for (int kk = 0; kk < 4; ++kk) {
    int o = (node0 + ar) * 128 + kk * 32 + ak;
    amH[kk] = *(const bf16x8*)&mgH[o];
    amL[kk] = *(const bf16x8*)&mgL[o];
    split8(&hf[o], &ahH[kk], &ahL[kk]);
  }
  // per-lane pre-swizzled global source pointers (12 x 1KB wave chunks / ct)
  const ushort_t* pq[12];
#pragma unroll
  for (int q = 0; q < 12; ++q) {
    int i = (q * 4 + w) * 64 + l;          // linear granule index in 48 KB
    int s = i >> 8, r = (i >> 4) & 15, gl = i & 15;
    int gsrc = gl ^ (r & 7);               // inverse of read-side XOR
    int mtx = s / 6, rem = s % 6, gate = rem >> 1, plane = rem & 1;
    const ushort_t* base = mtx ? (plane ? whhL : whhH) : (plane ? wihL : wihH);
    pq[q] = base + (gate * 128 + r) * 128 + gsrc * 8;
  }
  const char* lds = (const char*)smem;
  for (int ct = 0; ct < 8; ++ct) {
    int c0 = ct * 16;
    // async stage this ct's 48 KB of weights
#pragma unroll
    for (int q = 0; q < 12; ++q) {
      __builtin_amdgcn_global_load_lds(
          (const __attribute__((address_space(1))) void*)(pq[q] + c0 * 128),
          (__attribute__((address_space(3))) void*)(smem + (q * 4 + w) * 1024),
          16, 0, 0);
    }
    // prefetch previous-h (coalesced f32; own nodes/cols only)
    int col = c0 + ar;
    float hp[4];
#pragma unroll
    for (int j = 0; j < 4; ++j)
      hp[j] = hf[(node0 + hi * 4 + j) * 128 + col];
    __syncthreads();  // staging landed (compiler drains vmcnt before barrier)
    f32x4 air = {0.f,0.f,0.f,0.f}, aiz = air, ain = air;
    f32x4 ahr = air, ahz = air, ahn = air;
    int rbase = ar * 256;
    int rsw = (ar & 7) << 4;
#pragma unroll
    for (int kk = 0; kk < 4; ++kk) {
      int bin = rbase + ((kk * 64 + hi * 16) ^ rsw);
      bf16x8 B0  = *(const bf16x8*)(lds + 0 * 4096 + bin);
      bf16x8 B1  = *(const bf16x8*)(lds + 1 * 4096 + bin);
      bf16x8 B2  = *(const bf16x8*)(lds + 2 * 4096 + bin);
      bf16x8 B3  = *(const bf16x8*)(lds + 3 * 4096 + bin);
      bf16x8 B4  = *(const bf16x8*)(lds + 4 * 4096 + bin);
      bf16x8 B5  = *(const bf16x8*)(lds + 5 * 4096 + bin);
      bf16x8 B6  = *(const bf16x8*)(lds + 6 * 4096 + bin);
      bf16x8 B7  = *(const bf16x8*)(lds + 7 * 4096 + bin);
      bf16x8 B8  = *(const bf16x8*)(lds + 8 * 4096 + bin);
      bf16x8 B9  = *(const bf16x8*)(lds + 9 * 4096 + bin);
      bf16x8 B10 = *(const bf16x8*)(lds + 10 * 4096 + bin);
      bf16x8 B11 = *(const bf16x8*)(lds + 11 * 4096 + bin);
      air = __builtin_amdgcn_mfma_f32_16x16x32_bf16(amH[kk], B0,  air, 0, 0, 0);
      air = __builtin_amdgcn_mfma_f32_16x16x32_bf16(amH[kk], B1,  air, 0, 0, 0);
      air = __builtin_amdgcn_mfma_f32_16x16x32_bf16(amL[kk], B0,  air, 0, 0, 0);
      aiz = __builtin_amdgcn_mfma_f32_16x16x32_bf16(amH[kk], B2,  aiz, 0, 0, 0);
      aiz = __builtin_amdgcn_mfma_f32_16x16x32_bf16(amH[kk], B3,  aiz, 0, 0, 0);
      aiz = __builtin_amdgcn_mfma_f32_16x16x32_bf16(amL[kk], B2,  aiz, 0, 0, 0);
      ain = __builtin_amdgcn_mfma_f32_16x16x32_bf16(amH[kk], B4,  ain, 0, 0, 0);
      ain = __builtin_amdgcn_mfma_f32_16x16x32_bf16(amH[kk], B5,  ain, 0, 0, 0);
      ain = __builtin_amdgcn_mfma_f32_16x16x32_bf16(amL[kk], B4,  ain, 0, 0, 0);
      ahr = __builtin_amdgcn_mfma_f32_16x16x32_bf16(ahH[kk], B6,  ahr, 0, 0, 0);
      ahr = __builtin_amdgcn_mfma_f32_16x16x32_bf16(ahH[kk], B7,  ahr, 0, 0, 0);
      ahr = __builtin_amdgcn_mfma_f32_16x16x32_bf16(ahL[kk], B6,  ahr, 0, 0, 0);
      ahz = __builtin_amdgcn_mfma_f32_16x16x32_bf16(ahH[kk], B8,  ahz, 0, 0, 0);
      ahz = __builtin_amdgcn_mfma_f32_16x16x32_bf16(ahH[kk], B9,  ahz, 0, 0, 0);
      ahz = __builtin_amdgcn_mfma_f32_16x16x32_bf16(ahL[kk], B8,  ahz, 0, 0, 0);
      ahn = __builtin_amdgcn_mfma_f32_16x16x32_bf16(ahH[kk], B10, ahn, 0, 0, 0);
      ahn = __builtin_amdgcn_mfma_f32_16x16x32_bf16(ahH[kk], B11, ahn, 0, 0, 0);
      ahn = __builtin_amdgcn_mfma_f32_16x16x32_bf16(ahL[kk], B10, ahn, 0, 0, 0);
    }
    float bir = b_ih[col], biz = b_ih[128 + col], bin = b_ih[256 + col];
    float bhr = b_hh[col], bhz = b_hh[128 + col], bhn = b_hh[256 + col];
#pragma unroll
    for (int j = 0; j < 4; ++j) {
      int idx = (node0 + hi * 4 + j) * 128 + col;
      float gr = air[j] + bir + ahr[j] + bhr;
      float gz = aiz[j] + biz + ahz[j] + bhz;
      float r  = 1.f / (1.f + expf(-gr));
      float zg = 1.f / (1.f + expf(-gz));
      float nn = tanhf(ain[j] + bin + r * (ahn[j] + bhn));
      hf[idx] = (1.f - zg) * nn + zg * hp[j];
    }
    __syncthreads();  // all LDS reads done before next ct restages
  }
}

// ---------------- heads (f32 hf) ---------------------------------------------
__global__ __launch_bounds__(256) void k_musig(const float* __restrict__ hf,
                                               const float* __restrict__ w1,
                                               const float* __restrict__ b1,
                                               const float* __restrict__ w2,
                                               const float* __restrict__ b2,
                                               float* __restrict__ mu,
                                               float* __restrict__ sigma) {
  int t = threadIdx.x;
  int lane = t & 63, wv = t >> 6;
  int n = blockIdx.x * 4 + wv;
  float2 hv = *(const float2*)&hf[n * 128 + lane * 2];
  hv.x = fmaxf(hv.x, 0.f); hv.y = fmaxf(hv.y, 0.f);
  float2 w1v = *(const float2*)&w1[lane * 2];
  float2 w2v = *(const float2*)&w2[lane * 2];
  float a = hv.x * w1v.x + hv.y * w1v.y;
  float b = hv.x * w2v.x + hv.y * w2v.y;
#pragma unroll
  for (int off = 32; off > 0; off >>= 1) {
    a += __shfl_down(a, off);
    b += __shfl_down(b, off);
  }
  if (lane == 0) {
    mu[n] = a + b1[0];
    float v = b + b2[0];
    sigma[n] = fmaxf(v, 0.f) + log1pf(expf(-fabsf(v)));
  }
}

// ---------------- sampler (fp64 internal): analytic Cholesky ----------------
__device__ __forceinline__ double dscan_incl(double v, volatile double* buf, int i,
                                             double* tot) {
  buf[i] = v;
  __syncthreads();
#pragma unroll
  for (int off = 1; off < 256; off <<= 1) {
    double add = (i >= off) ? buf[i - off] : 0.0;
    __syncthreads();
    buf[i] += add;
    __syncthreads();
  }
  double incl = buf[i];
  *tot = buf[255];
  __syncthreads();
  return incl;
}

__global__ __launch_bounds__(256) void k_sample(const float* __restrict__ mu,
                                                const float* __restrict__ sigma,
                                                const float* __restrict__ zbuf,
                                                float* __restrict__ out) {
  __shared__ double buf[256];
  __shared__ double lastd[2];
  int g = blockIdx.x, i = threadIdx.x;
  int n = (g << 8) + i;
  double sig = (double)sigma[n], muv = (double)mu[n];
  bool isLast = (i == 255);
  if (isLast) { lastd[0] = sig; lastd[1] = muv; }
  double s   = isLast ? 0.0 : sig;
  double mui = isLast ? 0.0 : muv;
  double tS, tM, tY, tX;
  double inclS = dscan_incl(s, buf, i, &tS);
  dscan_incl(mui, buf, i, &tM);
  double sigLast = lastd[0], muLast = lastd[1];
  double denom = tS + sigLast;
  double c = -muLast / sigLast;
  double pre = inclS - s;
  double suffix  = denom - pre;
  double suffix1 = suffix - s;
  double sigL = isLast ? 0.0 : sqrt(s * suffix1 / suffix);
  double cL   = isLast ? 0.0 : (-s / (suffix * sigL));
  double zv   = isLast ? 0.0 : (double)zbuf[g * 255 + i];
  double y = cL * zv;
  double inclY = dscan_incl(y, buf, i, &tY);
  double Pz = inclY - y;
  double rm = s * c + mui - s * (c * tS + tM) / denom;
  double X = rm + s * Pz + sigL * zv;
  if (isLast) X = 0.0;
  dscan_incl(X, buf, i, &tX);
  out[n] = (float)(isLast ? (0.0 - tX) : X);
}

// ---------------------------------------------------------------------------
extern "C" void kernel_launch(void* const* d_in, const int* in_sizes, int n_in,
                              void* d_out, int out_size, void* d_ws, size_t ws_size,
                              hipStream_t stream) {
  const float* x      = (const float*)d_in[0];
  const float* lin0_w = (const float*)d_in[1];
  const float* ggc_w  = (const float*)d_in[2];
  const float* w_ih   = (const float*)d_in[3];
  const float* w_hh   = (const float*)d_in[4];
  const float* b_ih   = (const float*)d_in[5];
  const float* b_hh   = (const float*)d_in[6];
  const float* lin1_w = (const float*)d_in[7];
  const float* lin1_b = (const float*)d_in[8];
  const float* lin2_w = (const float*)d_in[9];
  const float* lin2_b = (const float*)d_in[10];
  const int*   ei     = (const int*)d_in[11];
  float* out = (float*)d_out;

  char* ws = (char*)d_ws;
  _Float16* m      = (_Float16*)(ws + 0);          // 8 MB (f16 messages)
  float*    hf     = (float*)   (ws + 16777216);   // 16 MB (f32 master h)
  ushort_t* mgH    = (ushort_t*)(ws + 33554432);   // 8 MB
  ushort_t* mgL    = (ushort_t*)(ws + 41943040);   // 8 MB
  ushort_t* wihH   = (ushort_t*)(ws + 50331648);   // 96 KB
  ushort_t* wihL   = (ushort_t*)(ws + 50429952);   // 96 KB
  ushort_t* whhH   = (ushort_t*)(ws + 50528256);   // 96 KB
  ushort_t* whhL   = (ushort_t*)(ws + 50626560);   // 96 KB
  ushort_t* GH     = (ushort_t*)(ws + 50724864);   // 128 KB [mu aliases]
  ushort_t* GL     = (ushort_t*)(ws + 50855936);   // 128 KB
  float*    zbuf   = (float*)   (ws + 50987008);   // 128 KB [counts aliases]
  float*    sigma  = (float*)   (ws + 51118080);   // 128 KB
  int*      row_ptr= (int*)     (ws + 51249152);   // 128.5 KB slot
  int*      srcs   = (int*)     (ws + 51380736);   // 2 MB
  float*    mu     = (float*)GH;                   // alias: used after all k_mm
  int*      counts = (int*)zbuf;                   // alias: CSR before k_zgen
  const size_t WS_NEEDED = 53477888;               // proven available
  if (ws_size < WS_NEEDED) return;

  // CSR build (counts aliases zbuf; done before k_zgen)
  k_zero<<<32, 256, 0, stream>>>(counts, N_NODES);
  k_hist<<<1024, 256, 0, stream>>>(ei, counts);
  k_scan<<<1, 1024, 0, stream>>>(counts, row_ptr);
  k_zero<<<32, 256, 0, stream>>>(counts, N_NODES);
  k_fill<<<1024, 256, 0, stream>>>(ei, row_ptr, counts, srcs);

  k_wprep<<<192, 256, 0, stream>>>(w_ih, w_hh, wihH, wihL, whhH, whhL);
  k_gprep<<<256, 256, 0, stream>>>(ggc_w, GH, GL);
  k_zgen<<<128, 256, 0, stream>>>(zbuf);
  k_lin0<<<8192, 256, 0, stream>>>(x, lin0_w, hf);

  for (int L = 0; L < 4; ++L) {
    k_mm_mfma<<<512, 256, 0, stream>>>(hf, GH + (size_t)L * 16384,
                                       GL + (size_t)L * 16384, m);
    k_agg<<<8192, 256, 0, stream>>>(m, mgH, mgL, row_ptr, srcs);
    k_gru_mfma<<<512, 256, 0, stream>>>(mgH, mgL, hf,
                                        wihH, wihL, whhH, whhL, b_ih, b_hh);
  }

  k_musig<<<8192, 256, 0, stream>>>(hf, lin1_w, lin1_b, lin2_w, lin2_b, mu, sigma);
  k_sample<<<128, 256, 0, stream>>>(mu, sigma, zbuf, out);
}

// Round 11
// 385.082 us; speedup vs baseline: 2.8168x; 1.0558x over previous
//
#include <hip/hip_runtime.h>
#include <stdint.h>

#define N_NODES 32768
#define N_EDGES 524288
#define NODE_MASK (N_NODES - 1)

typedef __attribute__((ext_vector_type(8))) short bf16x8;
typedef __attribute__((ext_vector_type(4))) float f32x4;
typedef __attribute__((ext_vector_type(2))) _Float16 f16x2;
typedef unsigned short ushort_t;

__device__ __forceinline__ ushort_t f2b(float f) {  // f32 -> bf16 RNE
  uint32_t u = __float_as_uint(f);
  return (ushort_t)((u + 0x7FFFu + ((u >> 16) & 1u)) >> 16);
}
__device__ __forceinline__ float b2f(uint32_t lo16) {
  return __uint_as_float(lo16 << 16);
}

// split f32[8] -> (hi trunc, lo RNE) bf16x8 planes
__device__ __forceinline__ void split8(const float* __restrict__ p,
                                       bf16x8* H, bf16x8* L) {
  bf16x8 h, lo;
#pragma unroll
  for (int i = 0; i < 8; ++i) {
    float x = p[i];
    uint32_t u = __float_as_uint(x);
    ushort_t hb = (ushort_t)(u >> 16);                 // truncation split
    float r = x - __uint_as_float((uint32_t)hb << 16); // exact residual
    h[i] = (short)hb;
    lo[i] = (short)f2b(r);
  }
  *H = h; *L = lo;
}

// ---------------- threefry2x32 (Threefry-20, partitionable mode) ------------
__device__ __forceinline__ uint32_t rotl32(uint32_t v, int r) {
  return (v << r) | (v >> (32 - r));
}

__device__ __forceinline__ void threefry2x32(uint32_t k0, uint32_t k1,
                                             uint32_t x0, uint32_t x1,
                                             uint32_t* o0, uint32_t* o1) {
  uint32_t k2 = k0 ^ k1 ^ 0x1BD11BDAu;
  x0 += k0; x1 += k1;
  x0 += x1; x1 = rotl32(x1, 13); x1 ^= x0;
  x0 += x1; x1 = rotl32(x1, 15); x1 ^= x0;
  x0 += x1; x1 = rotl32(x1, 26); x1 ^= x0;
  x0 += x1; x1 = rotl32(x1,  6); x1 ^= x0;
  x0 += k1; x1 += k2 + 1u;
  x0 += x1; x1 = rotl32(x1, 17); x1 ^= x0;
  x0 += x1; x1 = rotl32(x1, 29); x1 ^= x0;
  x0 += x1; x1 = rotl32(x1, 16); x1 ^= x0;
  x0 += x1; x1 = rotl32(x1, 24); x1 ^= x0;
  x0 += k2; x1 += k0 + 2u;
  x0 += x1; x1 = rotl32(x1, 13); x1 ^= x0;
  x0 += x1; x1 = rotl32(x1, 15); x1 ^= x0;
  x0 += x1; x1 = rotl32(x1, 26); x1 ^= x0;
  x0 += x1; x1 = rotl32(x1,  6); x1 ^= x0;
  x0 += k0; x1 += k1 + 3u;
  x0 += x1; x1 = rotl32(x1, 17); x1 ^= x0;
  x0 += x1; x1 = rotl32(x1, 29); x1 ^= x0;
  x0 += x1; x1 = rotl32(x1, 16); x1 ^= x0;
  x0 += x1; x1 = rotl32(x1, 24); x1 ^= x0;
  x0 += k1; x1 += k2 + 4u;
  x0 += x1; x1 = rotl32(x1, 13); x1 ^= x0;
  x0 += x1; x1 = rotl32(x1, 15); x1 ^= x0;
  x0 += x1; x1 = rotl32(x1, 26); x1 ^= x0;
  x0 += x1; x1 = rotl32(x1,  6); x1 ^= x0;
  x0 += k2; x1 += k0 + 5u;
  *o0 = x0; *o1 = x1;
}

__device__ __forceinline__ float bits_to_normal(uint32_t b) {
  uint32_t fb = (b >> 9) | 0x3F800000u;
  float f = __uint_as_float(fb) - 1.0f;          // [0,1)
  const float LO = -0.99999994f;
  float u = f * 2.0f + LO;
  u = fmaxf(LO, u);
  double zd = 1.4142135623730951 * erfinv((double)u);
  return (float)zd;
}

__global__ void k_zgen(float* __restrict__ z) {
  int i = blockIdx.x * blockDim.x + threadIdx.x;
  if (i >= 32640) return;
  uint32_t o0, o1;
  threefry2x32(0u, 123u, 0u, (uint32_t)i, &o0, &o1);
  z[i] = bits_to_normal(o0 ^ o1);
}

// ---------------- zero helper ------------------------------------------------
__global__ void k_zero(int* __restrict__ p, int n) {
  for (int i = blockIdx.x * blockDim.x + threadIdx.x; i < n;
       i += gridDim.x * blockDim.x)
    p[i] = 0;
}

// ---------------- CSR build (edge_index int32) ------------------------------
__global__ void k_hist(const int* __restrict__ ei, int* __restrict__ counts) {
  for (int e = blockIdx.x * blockDim.x + threadIdx.x; e < N_EDGES;
       e += gridDim.x * blockDim.x)
    atomicAdd(&counts[ei[N_EDGES + e] & NODE_MASK], 1);
}

__global__ __launch_bounds__(1024) void k_scan(const int* __restrict__ counts,
                                               int* __restrict__ row_ptr) {
  __shared__ int part[1024];
  int t = threadIdx.x;
  const int CH = N_NODES / 1024;  // 32
  int base = t * CH;
  int s = 0;
  for (int i = 0; i < CH; ++i) s += counts[base + i];
  part[t] = s;
  __syncthreads();
  for (int off = 1; off < 1024; off <<= 1) {
    int add = (t >= off) ? part[t - off] : 0;
    __syncthreads();
    part[t] += add;
    __syncthreads();
  }
  int run = (t == 0) ? 0 : part[t - 1];
  for (int i = 0; i < CH; ++i) { row_ptr[base + i] = run; run += counts[base + i]; }
  if (t == 1023) row_ptr[N_NODES] = run;
}

__global__ void k_fill(const int* __restrict__ ei, const int* __restrict__ row_ptr,
                       int* __restrict__ cursor, int* __restrict__ srcs) {
  for (int e = blockIdx.x * blockDim.x + threadIdx.x; e < N_EDGES;
       e += gridDim.x * blockDim.x) {
    int d = ei[N_EDGES + e] & NODE_MASK;
    int pos = row_ptr[d] + atomicAdd(&cursor[d], 1);
    srcs[pos] = ei[e] & NODE_MASK;
  }
}

// ---------------- whh prep: f32 -> (hi,lo) bf16 planes, [384][128] ----------
__global__ void k_wprep(const float* __restrict__ w_hh,
                        ushort_t* __restrict__ whhH, ushort_t* __restrict__ whhL) {
  int i = blockIdx.x * 256 + threadIdx.x;
  if (i >= 384 * 128) return;
  float b = w_hh[i];
  ushort_t bh = f2b(b);
  whhH[i] = bh; whhL[i] = f2b(b - b2f(bh));
}

// ---------------- combined weights: Wc[L][c][k] = sum_j G[L][k][j]*w_ih[c][j]
// (gi = hagg @ G @ w_ih^T = hagg @ Wc^T; Wc stored B^T-style [c][k], hi/lo)
__global__ void k_combine(const float* __restrict__ G,
                          const float* __restrict__ w_ih,
                          ushort_t* __restrict__ WcH, ushort_t* __restrict__ WcL) {
  int i = blockIdx.x * 256 + threadIdx.x;
  if (i >= 4 * 384 * 128) return;
  int L = i / (384 * 128), r = i % (384 * 128);
  int c = r >> 7, k = r & 127;
  const float* g  = G + L * 16384 + k * 128;  // G[L][k][:]
  const float* wv = w_ih + c * 128;           // w_ih[c][:]
  float acc = 0.f;
#pragma unroll 8
  for (int j = 0; j < 128; ++j) acc += g[j] * wv[j];
  ushort_t h = f2b(acc);
  WcH[i] = h; WcL[i] = f2b(acc - b2f(h));
}

// ---------------- lin0: hf (f32) + h16 (f16 shadow), padded to 128 ----------
__global__ __launch_bounds__(256) void k_lin0(const float* __restrict__ x,
                                              const float* __restrict__ w,
                                              float* __restrict__ hf,
                                              _Float16* __restrict__ h16) {
  __shared__ float sw[64][33];
  __shared__ float sx[4][32];
  int t = threadIdx.x;
  for (int e = t; e < 64 * 32; e += 256) sw[e >> 5][e & 31] = w[e];
  int node0 = blockIdx.x * 4;
  if (t < 128) sx[t >> 5][t & 31] = x[node0 * 32 + t];
  __syncthreads();
  int c = t & 63, nl = t >> 6;
  float acc = 0.f;
#pragma unroll
  for (int k = 0; k < 32; ++k) acc += sx[nl][k] * sw[c][k];
  float s = 1.f / (1.f + expf(-acc));
  int n = node0 + nl;
  hf[n * 128 + c] = s;
  hf[n * 128 + 64 + c] = 0.f;
  h16[n * 128 + c] = (_Float16)s;
  h16[n * 128 + 64 + c] = (_Float16)0.f;
}

// ---------------- segment-sum gather on h16: hi/lo bf16 planes out ----------
__global__ void k_agg(const _Float16* __restrict__ h16,
                      ushort_t* __restrict__ mgH, ushort_t* __restrict__ mgL,
                      const int* __restrict__ row_ptr, const int* __restrict__ srcs) {
  int wid = (blockIdx.x * blockDim.x + threadIdx.x) >> 6;
  int lane = threadIdx.x & 63;
  if (wid >= N_NODES) return;
  int beg = row_ptr[wid], end = row_ptr[wid + 1];
  float ax = 0.f, ay = 0.f, bx = 0.f, by = 0.f;
  int e = beg;
  for (; e + 2 <= end; e += 2) {
    int s0 = srcs[e] & NODE_MASK;
    int s1 = srcs[e + 1] & NODE_MASK;
    f16x2 v0 = *(const f16x2*)&h16[s0 * 128 + lane * 2];
    f16x2 v1 = *(const f16x2*)&h16[s1 * 128 + lane * 2];
    ax += (float)v0[0]; ay += (float)v0[1];
    bx += (float)v1[0]; by += (float)v1[1];
  }
  if (e < end) {
    int s0 = srcs[e] & NODE_MASK;
    f16x2 v0 = *(const f16x2*)&h16[s0 * 128 + lane * 2];
    ax += (float)v0[0]; ay += (float)v0[1];
  }
  ax += bx; ay += by;
  ushort_t xh = f2b(ax), yh = f2b(ay);
  ushort_t xl = f2b(ax - b2f(xh)), yl = f2b(ay - b2f(yh));
  *(uint32_t*)&mgH[wid * 128 + lane * 2] = (uint32_t)xh | ((uint32_t)yh << 16);
  *(uint32_t*)&mgL[wid * 128 + lane * 2] = (uint32_t)xl | ((uint32_t)yl << 16);
}

// ---------------- fused GRU via 3-term split MFMA ---------------------------
// gi = hagg @ Wc^T (+b_ih), gh = h @ w_hh^T (+b_hh); Wc = G @ w_ih^T folded.
// Weights staged per ct via global_load_lds (linear LDS dest, pre-swizzled
// global source; read side applies the same XOR involution). h kept f32;
// epilogue refreshes the f16 gather shadow.
__global__ __launch_bounds__(256, 2) void k_gru_mfma(
    const ushort_t* __restrict__ mgH, const ushort_t* __restrict__ mgL,
    float* __restrict__ hf, _Float16* __restrict__ h16,
    const ushort_t* __restrict__ WcH, const ushort_t* __restrict__ WcL,
    const ushort_t* __restrict__ whhH, const ushort_t* __restrict__ whhL,
    const float* __restrict__ b_ih, const float* __restrict__ b_hh) {
  __shared__ __align__(16) char smem[49152];  // 12 slices x 4 KB
  int t = threadIdx.x;
  int w = t >> 6, l = t & 63;
  int node0 = blockIdx.x * 64 + w * 16;
  int ar = l & 15, hi = l >> 4, ak = hi * 8;
  bf16x8 amH[4], amL[4], ahH[4], ahL[4];
#pragma unroll
  for (int kk = 0; kk < 4; ++kk) {
    int o = (node0 + ar) * 128 + kk * 32 + ak;
    amH[kk] = *(const bf16x8*)&mgH[o];
    amL[kk] = *(const bf16x8*)&mgL[o];
    split8(&hf[o], &ahH[kk], &ahL[kk]);
  }
  // per-lane pre-swizzled global source pointers (12 x 1KB wave chunks / ct)
  const ushort_t* pq[12];
#pragma unroll
  for (int q = 0; q < 12; ++q) {
    int i = (q * 4 + w) * 64 + l;          // linear granule index in 48 KB
    int s = i >> 8, r = (i >> 4) & 15, gl = i & 15;
    int gsrc = gl ^ (r & 7);               // inverse of read-side XOR
    int mtx = s / 6, rem = s % 6, gate = rem >> 1, plane = rem & 1;
    const ushort_t* base = mtx ? (plane ? whhL : whhH) : (plane ? WcL : WcH);
    pq[q] = base + (gate * 128 + r) * 128 + gsrc * 8;
  }
  const char* lds = (const char*)smem;
  for (int ct = 0; ct < 8; ++ct) {
    int c0 = ct * 16;
    // async stage this ct's 48 KB of weights
#pragma unroll
    for (int q = 0; q < 12; ++q) {
      __builtin_amdgcn_global_load_lds(
          (const __attribute__((address_space(1))) void*)(pq[q] + c0 * 128),
          (__attribute__((address_space(3))) void*)(smem + (q * 4 + w) * 1024),
          16, 0, 0);
    }
    // prefetch previous-h (coalesced f32; own nodes/cols only)
    int col = c0 + ar;
    float hp[4];
#pragma unroll
    for (int j = 0; j < 4; ++j)
      hp[j] = hf[(node0 + hi * 4 + j) * 128 + col];
    __syncthreads();  // staging landed (compiler drains vmcnt before barrier)
    f32x4 air = {0.f,0.f,0.f,0.f}, aiz = air, ain = air;
    f32x4 ahr = air, ahz = air, ahn = air;
    int rbase = ar * 256;
    int rsw = (ar & 7) << 4;
#pragma unroll
    for (int kk = 0; kk < 4; ++kk) {
      int bin = rbase + ((kk * 64 + hi * 16) ^ rsw);
      bf16x8 B0  = *(const bf16x8*)(lds + 0 * 4096 + bin);
      bf16x8 B1  = *(const bf16x8*)(lds + 1 * 4096 + bin);
      bf16x8 B2  = *(const bf16x8*)(lds + 2 * 4096 + bin);
      bf16x8 B3  = *(const bf16x8*)(lds + 3 * 4096 + bin);
      bf16x8 B4  = *(const bf16x8*)(lds + 4 * 4096 + bin);
      bf16x8 B5  = *(const bf16x8*)(lds + 5 * 4096 + bin);
      bf16x8 B6  = *(const bf16x8*)(lds + 6 * 4096 + bin);
      bf16x8 B7  = *(const bf16x8*)(lds + 7 * 4096 + bin);
      bf16x8 B8  = *(const bf16x8*)(lds + 8 * 4096 + bin);
      bf16x8 B9  = *(const bf16x8*)(lds + 9 * 4096 + bin);
      bf16x8 B10 = *(const bf16x8*)(lds + 10 * 4096 + bin);
      bf16x8 B11 = *(const bf16x8*)(lds + 11 * 4096 + bin);
      air = __builtin_amdgcn_mfma_f32_16x16x32_bf16(amH[kk], B0,  air, 0, 0, 0);
      air = __builtin_amdgcn_mfma_f32_16x16x32_bf16(amH[kk], B1,  air, 0, 0, 0);
      air = __builtin_amdgcn_mfma_f32_16x16x32_bf16(amL[kk], B0,  air, 0, 0, 0);
      aiz = __builtin_amdgcn_mfma_f32_16x16x32_bf16(amH[kk], B2,  aiz, 0, 0, 0);
      aiz = __builtin_amdgcn_mfma_f32_16x16x32_bf16(amH[kk], B3,  aiz, 0, 0, 0);
      aiz = __builtin_amdgcn_mfma_f32_16x16x32_bf16(amL[kk], B2,  aiz, 0, 0, 0);
      ain = __builtin_amdgcn_mfma_f32_16x16x32_bf16(amH[kk], B4,  ain, 0, 0, 0);
      ain = __builtin_amdgcn_mfma_f32_16x16x32_bf16(amH[kk], B5,  ain, 0, 0, 0);
      ain = __builtin_amdgcn_mfma_f32_16x16x32_bf16(amL[kk], B4,  ain, 0, 0, 0);
      ahr = __builtin_amdgcn_mfma_f32_16x16x32_bf16(ahH[kk], B6,  ahr, 0, 0, 0);
      ahr = __builtin_amdgcn_mfma_f32_16x16x32_bf16(ahH[kk], B7,  ahr, 0, 0, 0);
      ahr = __builtin_amdgcn_mfma_f32_16x16x32_bf16(ahL[kk], B6,  ahr, 0, 0, 0);
      ahz = __builtin_amdgcn_mfma_f32_16x16x32_bf16(ahH[kk], B8,  ahz, 0, 0, 0);
      ahz = __builtin_amdgcn_mfma_f32_16x16x32_bf16(ahH[kk], B9,  ahz, 0, 0, 0);
      ahz = __builtin_amdgcn_mfma_f32_16x16x32_bf16(ahL[kk], B8,  ahz, 0, 0, 0);
      ahn = __builtin_amdgcn_mfma_f32_16x16x32_bf16(ahH[kk], B10, ahn, 0, 0, 0);
      ahn = __builtin_amdgcn_mfma_f32_16x16x32_bf16(ahH[kk], B11, ahn, 0, 0, 0);
      ahn = __builtin_amdgcn_mfma_f32_16x16x32_bf16(ahL[kk], B10, ahn, 0, 0, 0);
    }
    float bir = b_ih[col], biz = b_ih[128 + col], bin = b_ih[256 + col];
    float bhr = b_hh[col], bhz = b_hh[128 + col], bhn = b_hh[256 + col];
#pragma unroll
    for (int j = 0; j < 4; ++j) {
      int idx = (node0 + hi * 4 + j) * 128 + col;
      float gr = air[j] + bir + ahr[j] + bhr;
      float gz = aiz[j] + biz + ahz[j] + bhz;
      float r  = 1.f / (1.f + expf(-gr));
      float zg = 1.f / (1.f + expf(-gz));
      float nn = tanhf(ain[j] + bin + r * (ahn[j] + bhn));
      float hn = (1.f - zg) * nn + zg * hp[j];
      hf[idx] = hn;
      h16[idx] = (_Float16)hn;
    }
    __syncthreads();  // all LDS reads done before next ct restages
  }
}

// ---------------- heads (f32 hf) ---------------------------------------------
__global__ __launch_bounds__(256) void k_musig(const float* __restrict__ hf,
                                               const float* __restrict__ w1,
                                               const float* __restrict__ b1,
                                               const float* __restrict__ w2,
                                               const float* __restrict__ b2,
                                               float* __restrict__ mu,
                                               float* __restrict__ sigma) {
  int t = threadIdx.x;
  int lane = t & 63, wv = t >> 6;
  int n = blockIdx.x * 4 + wv;
  float2 hv = *(const float2*)&hf[n * 128 + lane * 2];
  hv.x = fmaxf(hv.x, 0.f); hv.y = fmaxf(hv.y, 0.f);
  float2 w1v = *(const float2*)&w1[lane * 2];
  float2 w2v = *(const float2*)&w2[lane * 2];
  float a = hv.x * w1v.x + hv.y * w1v.y;
  float b = hv.x * w2v.x + hv.y * w2v.y;
#pragma unroll
  for (int off = 32; off > 0; off >>= 1) {
    a += __shfl_down(a, off);
    b += __shfl_down(b, off);
  }
  if (lane == 0) {
    mu[n] = a + b1[0];
    float v = b + b2[0];
    sigma[n] = fmaxf(v, 0.f) + log1pf(expf(-fabsf(v)));
  }
}

// ---------------- sampler (fp64 internal): analytic Cholesky ----------------
__device__ __forceinline__ double dscan_incl(double v, volatile double* buf, int i,
                                             double* tot) {
  buf[i] = v;
  __syncthreads();
#pragma unroll
  for (int off = 1; off < 256; off <<= 1) {
    double add = (i >= off) ? buf[i - off] : 0.0;
    __syncthreads();
    buf[i] += add;
    __syncthreads();
  }
  double incl = buf[i];
  *tot = buf[255];
  __syncthreads();
  return incl;
}

__global__ __launch_bounds__(256) void k_sample(const float* __restrict__ mu,
                                                const float* __restrict__ sigma,
                                                const float* __restrict__ zbuf,
                                                float* __restrict__ out) {
  __shared__ double buf[256];
  __shared__ double lastd[2];
  int g = blockIdx.x, i = threadIdx.x;
  int n = (g << 8) + i;
  double sig = (double)sigma[n], muv = (double)mu[n];
  bool isLast = (i == 255);
  if (isLast) { lastd[0] = sig; lastd[1] = muv; }
  double s   = isLast ? 0.0 : sig;
  double mui = isLast ? 0.0 : muv;
  double tS, tM, tY, tX;
  double inclS = dscan_incl(s, buf, i, &tS);
  dscan_incl(mui, buf, i, &tM);
  double sigLast = lastd[0], muLast = lastd[1];
  double denom = tS + sigLast;
  double c = -muLast / sigLast;
  double pre = inclS - s;
  double suffix  = denom - pre;
  double suffix1 = suffix - s;
  double sigL = isLast ? 0.0 : sqrt(s * suffix1 / suffix);
  double cL   = isLast ? 0.0 : (-s / (suffix * sigL));
  double zv   = isLast ? 0.0 : (double)zbuf[g * 255 + i];
  double y = cL * zv;
  double inclY = dscan_incl(y, buf, i, &tY);
  double Pz = inclY - y;
  double rm = s * c + mui - s * (c * tS + tM) / denom;
  double X = rm + s * Pz + sigL * zv;
  if (isLast) X = 0.0;
  dscan_incl(X, buf, i, &tX);
  out[n] = (float)(isLast ? (0.0 - tX) : X);
}

// ---------------------------------------------------------------------------
extern "C" void kernel_launch(void* const* d_in, const int* in_sizes, int n_in,
                              void* d_out, int out_size, void* d_ws, size_t ws_size,
                              hipStream_t stream) {
  const float* x      = (const float*)d_in[0];
  const float* lin0_w = (const float*)d_in[1];
  const float* ggc_w  = (const float*)d_in[2];
  const float* w_ih   = (const float*)d_in[3];
  const float* w_hh   = (const float*)d_in[4];
  const float* b_ih   = (const float*)d_in[5];
  const float* b_hh   = (const float*)d_in[6];
  const float* lin1_w = (const float*)d_in[7];
  const float* lin1_b = (const float*)d_in[8];
  const float* lin2_w = (const float*)d_in[9];
  const float* lin2_b = (const float*)d_in[10];
  const int*   ei     = (const int*)d_in[11];
  float* out = (float*)d_out;

  char* ws = (char*)d_ws;
  float*    hf     = (float*)   (ws + 0);          // 16 MB (f32 master h)
  _Float16* h16    = (_Float16*)(ws + 16777216);   // 8 MB (f16 gather shadow)
  ushort_t* mgH    = (ushort_t*)(ws + 25165824);   // 8 MB (hagg hi plane)
  ushort_t* mgL    = (ushort_t*)(ws + 33554432);   // 8 MB (hagg lo plane)
  ushort_t* WcH    = (ushort_t*)(ws + 41943040);   // 384 KB (4 layers)
  ushort_t* WcL    = (ushort_t*)(ws + 42336256);   // 384 KB
  ushort_t* whhH   = (ushort_t*)(ws + 42729472);   // 96 KB
  ushort_t* whhL   = (ushort_t*)(ws + 42827776);   // 96 KB
  float*    zbuf   = (float*)   (ws + 42926080);   // 128 KB [counts aliases]
  float*    mu     = (float*)   (ws + 43057152);   // 128 KB
  float*    sigma  = (float*)   (ws + 43188224);   // 128 KB
  int*      row_ptr= (int*)     (ws + 43319296);   // 128.5 KB slot
  int*      srcs   = (int*)     (ws + 43450880);   // 2 MB -> ends 45548032
  int*      counts = (int*)zbuf;                   // alias: CSR before k_zgen
  const size_t WS_NEEDED = 45548032;               // < proven 53477888
  if (ws_size < WS_NEEDED) return;

  // CSR build (counts aliases zbuf; done before k_zgen)
  k_zero<<<32, 256, 0, stream>>>(counts, N_NODES);
  k_hist<<<1024, 256, 0, stream>>>(ei, counts);
  k_scan<<<1, 1024, 0, stream>>>(counts, row_ptr);
  k_zero<<<32, 256, 0, stream>>>(counts, N_NODES);
  k_fill<<<1024, 256, 0, stream>>>(ei, row_ptr, counts, srcs);

  k_wprep<<<192, 256, 0, stream>>>(w_hh, whhH, whhL);
  k_combine<<<768, 256, 0, stream>>>(ggc_w, w_ih, WcH, WcL);
  k_zgen<<<128, 256, 0, stream>>>(zbuf);
  k_lin0<<<8192, 256, 0, stream>>>(x, lin0_w, hf, h16);

  for (int L = 0; L < 4; ++L) {
    k_agg<<<8192, 256, 0, stream>>>(h16, mgH, mgL, row_ptr, srcs);
    k_gru_mfma<<<512, 256, 0, stream>>>(mgH, mgL, hf, h16,
                                        WcH + (size_t)L * 49152,
                                        WcL + (size_t)L * 49152,
                                        whhH, whhL, b_ih, b_hh);
  }

  k_musig<<<8192, 256, 0, stream>>>(hf, lin1_w, lin1_b, lin2_w, lin2_b, mu, sigma);
  k_sample<<<128, 256, 0, stream>>>(mu, sigma, zbuf, out);
}

// Round 12
// 347.753 us; speedup vs baseline: 3.1192x; 1.1073x over previous
//
#include <hip/hip_runtime.h>
#include <stdint.h>

#define N_NODES 32768
#define N_EDGES 524288
#define NODE_MASK (N_NODES - 1)

typedef __attribute__((ext_vector_type(8))) short bf16x8;
typedef __attribute__((ext_vector_type(4))) float f32x4;
typedef __attribute__((ext_vector_type(8))) _Float16 f16x8;
typedef unsigned short ushort_t;

__device__ __forceinline__ ushort_t f2b(float f) {  // f32 -> bf16 RNE
  uint32_t u = __float_as_uint(f);
  return (ushort_t)((u + 0x7FFFu + ((u >> 16) & 1u)) >> 16);
}
__device__ __forceinline__ float b2f(uint32_t lo16) {
  return __uint_as_float(lo16 << 16);
}

// split f32[8] -> (hi trunc, lo RNE) bf16x8 planes
__device__ __forceinline__ void split8(const float* __restrict__ p,
                                       bf16x8* H, bf16x8* L) {
  bf16x8 h, lo;
#pragma unroll
  for (int i = 0; i < 8; ++i) {
    float x = p[i];
    uint32_t u = __float_as_uint(x);
    ushort_t hb = (ushort_t)(u >> 16);                 // truncation split
    float r = x - __uint_as_float((uint32_t)hb << 16); // exact residual
    h[i] = (short)hb;
    lo[i] = (short)f2b(r);
  }
  *H = h; *L = lo;
}

// ---------------- threefry2x32 (Threefry-20, partitionable mode) ------------
__device__ __forceinline__ uint32_t rotl32(uint32_t v, int r) {
  return (v << r) | (v >> (32 - r));
}

__device__ __forceinline__ void threefry2x32(uint32_t k0, uint32_t k1,
                                             uint32_t x0, uint32_t x1,
                                             uint32_t* o0, uint32_t* o1) {
  uint32_t k2 = k0 ^ k1 ^ 0x1BD11BDAu;
  x0 += k0; x1 += k1;
  x0 += x1; x1 = rotl32(x1, 13); x1 ^= x0;
  x0 += x1; x1 = rotl32(x1, 15); x1 ^= x0;
  x0 += x1; x1 = rotl32(x1, 26); x1 ^= x0;
  x0 += x1; x1 = rotl32(x1,  6); x1 ^= x0;
  x0 += k1; x1 += k2 + 1u;
  x0 += x1; x1 = rotl32(x1, 17); x1 ^= x0;
  x0 += x1; x1 = rotl32(x1, 29); x1 ^= x0;
  x0 += x1; x1 = rotl32(x1, 16); x1 ^= x0;
  x0 += x1; x1 = rotl32(x1, 24); x1 ^= x0;
  x0 += k2; x1 += k0 + 2u;
  x0 += x1; x1 = rotl32(x1, 13); x1 ^= x0;
  x0 += x1; x1 = rotl32(x1, 15); x1 ^= x0;
  x0 += x1; x1 = rotl32(x1, 26); x1 ^= x0;
  x0 += x1; x1 = rotl32(x1,  6); x1 ^= x0;
  x0 += k0; x1 += k1 + 3u;
  x0 += x1; x1 = rotl32(x1, 17); x1 ^= x0;
  x0 += x1; x1 = rotl32(x1, 29); x1 ^= x0;
  x0 += x1; x1 = rotl32(x1, 16); x1 ^= x0;
  x0 += x1; x1 = rotl32(x1, 24); x1 ^= x0;
  x0 += k1; x1 += k2 + 4u;
  x0 += x1; x1 = rotl32(x1, 13); x1 ^= x0;
  x0 += x1; x1 = rotl32(x1, 15); x1 ^= x0;
  x0 += x1; x1 = rotl32(x1, 26); x1 ^= x0;
  x0 += x1; x1 = rotl32(x1,  6); x1 ^= x0;
  x0 += k2; x1 += k0 + 5u;
  *o0 = x0; *o1 = x1;
}

__device__ __forceinline__ float bits_to_normal(uint32_t b) {
  uint32_t fb = (b >> 9) | 0x3F800000u;
  float f = __uint_as_float(fb) - 1.0f;          // [0,1)
  const float LO = -0.99999994f;
  float u = f * 2.0f + LO;
  u = fmaxf(LO, u);
  double zd = 1.4142135623730951 * erfinv((double)u);
  return (float)zd;
}

__global__ void k_zgen(float* __restrict__ z) {
  int i = blockIdx.x * blockDim.x + threadIdx.x;
  if (i >= 32640) return;
  uint32_t o0, o1;
  threefry2x32(0u, 123u, 0u, (uint32_t)i, &o0, &o1);
  z[i] = bits_to_normal(o0 ^ o1);
}

// ---------------- zero helper ------------------------------------------------
__global__ void k_zero(int* __restrict__ p, int n) {
  for (int i = blockIdx.x * blockDim.x + threadIdx.x; i < n;
       i += gridDim.x * blockDim.x)
    p[i] = 0;
}

// ---------------- CSR build (edge_index int32) ------------------------------
__global__ void k_hist(const int* __restrict__ ei, int* __restrict__ counts) {
  for (int e = blockIdx.x * blockDim.x + threadIdx.x; e < N_EDGES;
       e += gridDim.x * blockDim.x)
    atomicAdd(&counts[ei[N_EDGES + e] & NODE_MASK], 1);
}

__global__ __launch_bounds__(1024) void k_scan(const int* __restrict__ counts,
                                               int* __restrict__ row_ptr) {
  __shared__ int part[1024];
  int t = threadIdx.x;
  const int CH = N_NODES / 1024;  // 32
  int base = t * CH;
  int s = 0;
  for (int i = 0; i < CH; ++i) s += counts[base + i];
  part[t] = s;
  __syncthreads();
  for (int off = 1; off < 1024; off <<= 1) {
    int add = (t >= off) ? part[t - off] : 0;
    __syncthreads();
    part[t] += add;
    __syncthreads();
  }
  int run = (t == 0) ? 0 : part[t - 1];
  for (int i = 0; i < CH; ++i) { row_ptr[base + i] = run; run += counts[base + i]; }
  if (t == 1023) row_ptr[N_NODES] = run;
}

__global__ void k_fill(const int* __restrict__ ei, const int* __restrict__ row_ptr,
                       int* __restrict__ cursor, int* __restrict__ srcs) {
  for (int e = blockIdx.x * blockDim.x + threadIdx.x; e < N_EDGES;
       e += gridDim.x * blockDim.x) {
    int d = ei[N_EDGES + e] & NODE_MASK;
    int pos = row_ptr[d] + atomicAdd(&cursor[d], 1);
    srcs[pos] = ei[e] & NODE_MASK;
  }
}

// ---------------- whh prep: f32 -> (hi,lo) bf16 planes, [384][128] ----------
__global__ void k_wprep(const float* __restrict__ w_hh,
                        ushort_t* __restrict__ whhH, ushort_t* __restrict__ whhL) {
  int i = blockIdx.x * 256 + threadIdx.x;
  if (i >= 384 * 128) return;
  float b = w_hh[i];
  ushort_t bh = f2b(b);
  whhH[i] = bh; whhL[i] = f2b(b - b2f(bh));
}

// ---------------- combined weights: Wc[L][c][k] = sum_j G[L][k][j]*w_ih[c][j]
__global__ void k_combine(const float* __restrict__ G,
                          const float* __restrict__ w_ih,
                          ushort_t* __restrict__ WcH, ushort_t* __restrict__ WcL) {
  int i = blockIdx.x * 256 + threadIdx.x;
  if (i >= 4 * 384 * 128) return;
  int L = i / (384 * 128), r = i % (384 * 128);
  int c = r >> 7, k = r & 127;
  const float* g  = G + L * 16384 + k * 128;  // G[L][k][:]
  const float* wv = w_ih + c * 128;           // w_ih[c][:]
  float acc = 0.f;
#pragma unroll 8
  for (int j = 0; j < 128; ++j) acc += g[j] * wv[j];
  ushort_t h = f2b(acc);
  WcH[i] = h; WcL[i] = f2b(acc - b2f(h));
}

// ---------------- lin0: hf (f32) + h16 (f16 shadow), padded to 128 ----------
__global__ __launch_bounds__(256) void k_lin0(const float* __restrict__ x,
                                              const float* __restrict__ w,
                                              float* __restrict__ hf,
                                              _Float16* __restrict__ h16) {
  __shared__ float sw[64][33];
  __shared__ float sx[4][32];
  int t = threadIdx.x;
  for (int e = t; e < 64 * 32; e += 256) sw[e >> 5][e & 31] = w[e];
  int node0 = blockIdx.x * 4;
  if (t < 128) sx[t >> 5][t & 31] = x[node0 * 32 + t];
  __syncthreads();
  int c = t & 63, nl = t >> 6;
  float acc = 0.f;
#pragma unroll
  for (int k = 0; k < 32; ++k) acc += sx[nl][k] * sw[c][k];
  float s = 1.f / (1.f + expf(-acc));
  int n = node0 + nl;
  hf[n * 128 + c] = s;
  hf[n * 128 + 64 + c] = 0.f;
  h16[n * 128 + c] = (_Float16)s;
  h16[n * 128 + 64 + c] = (_Float16)0.f;
}

// ---------------- segment-sum gather: 16B/lane, 4 edges/instr, f32 out ------
// lane l: cols (l&15)*8..+7, edge subgroup l>>4; xor-reduce over subgroups.
__global__ void k_agg(const _Float16* __restrict__ h16,
                      float* __restrict__ mg,
                      const int* __restrict__ row_ptr, const int* __restrict__ srcs) {
  int wid = (blockIdx.x * blockDim.x + threadIdx.x) >> 6;
  int lane = threadIdx.x & 63;
  if (wid >= N_NODES) return;
  int cg = lane & 15, eg = lane >> 4;
  int beg = row_ptr[wid], end = row_ptr[wid + 1];
  float acc[8];
#pragma unroll
  for (int i = 0; i < 8; ++i) acc[i] = 0.f;
  for (int e = beg + eg; e < end; e += 4) {
    int s = srcs[e] & NODE_MASK;
    f16x8 v = *(const f16x8*)&h16[s * 128 + cg * 8];
#pragma unroll
    for (int i = 0; i < 8; ++i) acc[i] += (float)v[i];
  }
#pragma unroll
  for (int i = 0; i < 8; ++i) {
    acc[i] += __shfl_xor(acc[i], 16);
    acc[i] += __shfl_xor(acc[i], 32);
  }
  if (eg == 0) {
    float4 lo = make_float4(acc[0], acc[1], acc[2], acc[3]);
    float4 hi = make_float4(acc[4], acc[5], acc[6], acc[7]);
    *(float4*)&mg[wid * 128 + cg * 8] = lo;
    *(float4*)&mg[wid * 128 + cg * 8 + 4] = hi;
  }
}

// ---------------- fused GRU via 3-term split MFMA ---------------------------
// gi = hagg @ Wc^T (+b_ih), gh = h @ w_hh^T (+b_hh); Wc = G @ w_ih^T folded.
// Weights staged per ct via global_load_lds (linear LDS dest, pre-swizzled
// global source; read side applies the same XOR involution). h kept f32;
// epilogue refreshes the f16 gather shadow.
__global__ __launch_bounds__(256, 2) void k_gru_mfma(
    const float* __restrict__ mg,
    float* __restrict__ hf, _Float16* __restrict__ h16,
    const ushort_t* __restrict__ WcH, const ushort_t* __restrict__ WcL,
    const ushort_t* __restrict__ whhH, const ushort_t* __restrict__ whhL,
    const float* __restrict__ b_ih, const float* __restrict__ b_hh) {
  __shared__ __align__(16) char smem[49152];  // 12 slices x 4 KB
  int t = threadIdx.x;
  int w = t >> 6, l = t & 63;
  int node0 = blockIdx.x * 64 + w * 16;
  int ar = l & 15, hi = l >> 4, ak = hi * 8;
  bf16x8 amH[4], amL[4], ahH[4], ahL[4];
#pragma unroll
  for (int kk = 0; kk < 4; ++kk) {
    int o = (node0 + ar) * 128 + kk * 32 + ak;
    split8(&mg[o], &amH[kk], &amL[kk]);
    split8(&hf[o], &ahH[kk], &ahL[kk]);
  }
  // per-lane pre-swizzled global source pointers (12 x 1KB wave chunks / ct)
  const ushort_t* pq[12];
#pragma unroll
  for (int q = 0; q < 12; ++q) {
    int i = (q * 4 + w) * 64 + l;          // linear granule index in 48 KB
    int s = i >> 8, r = (i >> 4) & 15, gl = i & 15;
    int gsrc = gl ^ (r & 7);               // inverse of read-side XOR
    int mtx = s / 6, rem = s % 6, gate = rem >> 1, plane = rem & 1;
    const ushort_t* base = mtx ? (plane ? whhL : whhH) : (plane ? WcL : WcH);
    pq[q] = base + (gate * 128 + r) * 128 + gsrc * 8;
  }
  const char* lds = (const char*)smem;
  for (int ct = 0; ct < 8; ++ct) {
    int c0 = ct * 16;
    // async stage this ct's 48 KB of weights
#pragma unroll
    for (int q = 0; q < 12; ++q) {
      __builtin_amdgcn_global_load_lds(
          (const __attribute__((address_space(1))) void*)(pq[q] + c0 * 128),
          (__attribute__((address_space(3))) void*)(smem + (q * 4 + w) * 1024),
          16, 0, 0);
    }
    // prefetch previous-h (coalesced f32; own nodes/cols only)
    int col = c0 + ar;
    float hp[4];
#pragma unroll
    for (int j = 0; j < 4; ++j)
      hp[j] = hf[(node0 + hi * 4 + j) * 128 + col];
    __syncthreads();  // staging landed (compiler drains vmcnt before barrier)
    f32x4 air = {0.f,0.f,0.f,0.f}, aiz = air, ain = air;
    f32x4 ahr = air, ahz = air, ahn = air;
    int rbase = ar * 256;
    int rsw = (ar & 7) << 4;
#pragma unroll
    for (int kk = 0; kk < 4; ++kk) {
      int bin = rbase + ((kk * 64 + hi * 16) ^ rsw);
      bf16x8 B0  = *(const bf16x8*)(lds + 0 * 4096 + bin);
      bf16x8 B1  = *(const bf16x8*)(lds + 1 * 4096 + bin);
      bf16x8 B2  = *(const bf16x8*)(lds + 2 * 4096 + bin);
      bf16x8 B3  = *(const bf16x8*)(lds + 3 * 4096 + bin);
      bf16x8 B4  = *(const bf16x8*)(lds + 4 * 4096 + bin);
      bf16x8 B5  = *(const bf16x8*)(lds + 5 * 4096 + bin);
      bf16x8 B6  = *(const bf16x8*)(lds + 6 * 4096 + bin);
      bf16x8 B7  = *(const bf16x8*)(lds + 7 * 4096 + bin);
      bf16x8 B8  = *(const bf16x8*)(lds + 8 * 4096 + bin);
      bf16x8 B9  = *(const bf16x8*)(lds + 9 * 4096 + bin);
      bf16x8 B10 = *(const bf16x8*)(lds + 10 * 4096 + bin);
      bf16x8 B11 = *(const bf16x8*)(lds + 11 * 4096 + bin);
      air = __builtin_amdgcn_mfma_f32_16x16x32_bf16(amH[kk], B0,  air, 0, 0, 0);
      air = __builtin_amdgcn_mfma_f32_16x16x32_bf16(amH[kk], B1,  air, 0, 0, 0);
      air = __builtin_amdgcn_mfma_f32_16x16x32_bf16(amL[kk], B0,  air, 0, 0, 0);
      aiz = __builtin_amdgcn_mfma_f32_16x16x32_bf16(amH[kk], B2,  aiz, 0, 0, 0);
      aiz = __builtin_amdgcn_mfma_f32_16x16x32_bf16(amH[kk], B3,  aiz, 0, 0, 0);
      aiz = __builtin_amdgcn_mfma_f32_16x16x32_bf16(amL[kk], B2,  aiz, 0, 0, 0);
      ain = __builtin_amdgcn_mfma_f32_16x16x32_bf16(amH[kk], B4,  ain, 0, 0, 0);
      ain = __builtin_amdgcn_mfma_f32_16x16x32_bf16(amH[kk], B5,  ain, 0, 0, 0);
      ain = __builtin_amdgcn_mfma_f32_16x16x32_bf16(amL[kk], B4,  ain, 0, 0, 0);
      ahr = __builtin_amdgcn_mfma_f32_16x16x32_bf16(ahH[kk], B6,  ahr, 0, 0, 0);
      ahr = __builtin_amdgcn_mfma_f32_16x16x32_bf16(ahH[kk], B7,  ahr, 0, 0, 0);
      ahr = __builtin_amdgcn_mfma_f32_16x16x32_bf16(ahL[kk], B6,  ahr, 0, 0, 0);
      ahz = __builtin_amdgcn_mfma_f32_16x16x32_bf16(ahH[kk], B8,  ahz, 0, 0, 0);
      ahz = __builtin_amdgcn_mfma_f32_16x16x32_bf16(ahH[kk], B9,  ahz, 0, 0, 0);
      ahz = __builtin_amdgcn_mfma_f32_16x16x32_bf16(ahL[kk], B8,  ahz, 0, 0, 0);
      ahn = __builtin_amdgcn_mfma_f32_16x16x32_bf16(ahH[kk], B10, ahn, 0, 0, 0);
      ahn = __builtin_amdgcn_mfma_f32_16x16x32_bf16(ahH[kk], B11, ahn, 0, 0, 0);
      ahn = __builtin_amdgcn_mfma_f32_16x16x32_bf16(ahL[kk], B10, ahn, 0, 0, 0);
    }
    float bir = b_ih[col], biz = b_ih[128 + col], bin = b_ih[256 + col];
    float bhr = b_hh[col], bhz = b_hh[128 + col], bhn = b_hh[256 + col];
#pragma unroll
    for (int j = 0; j < 4; ++j) {
      int idx = (node0 + hi * 4 + j) * 128 + col;
      float gr = air[j] + bir + ahr[j] + bhr;
      float gz = aiz[j] + biz + ahz[j] + bhz;
      float r  = 1.f / (1.f + expf(-gr));
      float zg = 1.f / (1.f + expf(-gz));
      float nn = tanhf(ain[j] + bin + r * (ahn[j] + bhn));
      float hn = (1.f - zg) * nn + zg * hp[j];
      hf[idx] = hn;
      h16[idx] = (_Float16)hn;
    }
    __syncthreads();  // all LDS reads done before next ct restages
  }
}

// ---------------- heads (f32 hf) ---------------------------------------------
__global__ __launch_bounds__(256) void k_musig(const float* __restrict__ hf,
                                               const float* __restrict__ w1,
                                               const float* __restrict__ b1,
                                               const float* __restrict__ w2,
                                               const float* __restrict__ b2,
                                               float* __restrict__ mu,
                                               float* __restrict__ sigma) {
  int t = threadIdx.x;
  int lane = t & 63, wv = t >> 6;
  int n = blockIdx.x * 4 + wv;
  float2 hv = *(const float2*)&hf[n * 128 + lane * 2];
  hv.x = fmaxf(hv.x, 0.f); hv.y = fmaxf(hv.y, 0.f);
  float2 w1v = *(const float2*)&w1[lane * 2];
  float2 w2v = *(const float2*)&w2[lane * 2];
  float a = hv.x * w1v.x + hv.y * w1v.y;
  float b = hv.x * w2v.x + hv.y * w2v.y;
#pragma unroll
  for (int off = 32; off > 0; off >>= 1) {
    a += __shfl_down(a, off);
    b += __shfl_down(b, off);
  }
  if (lane == 0) {
    mu[n] = a + b1[0];
    float v = b + b2[0];
    sigma[n] = fmaxf(v, 0.f) + log1pf(expf(-fabsf(v)));
  }
}

// ---------------- sampler (fp64 internal): analytic Cholesky ----------------
__device__ __forceinline__ double dscan_incl(double v, volatile double* buf, int i,
                                             double* tot) {
  buf[i] = v;
  __syncthreads();
#pragma unroll
  for (int off = 1; off < 256; off <<= 1) {
    double add = (i >= off) ? buf[i - off] : 0.0;
    __syncthreads();
    buf[i] += add;
    __syncthreads();
  }
  double incl = buf[i];
  *tot = buf[255];
  __syncthreads();
  return incl;
}

__global__ __launch_bounds__(256) void k_sample(const float* __restrict__ mu,
                                                const float* __restrict__ sigma,
                                                const float* __restrict__ zbuf,
                                                float* __restrict__ out) {
  __shared__ double buf[256];
  __shared__ double lastd[2];
  int g = blockIdx.x, i = threadIdx.x;
  int n = (g << 8) + i;
  double sig = (double)sigma[n], muv = (double)mu[n];
  bool isLast = (i == 255);
  if (isLast) { lastd[0] = sig; lastd[1] = muv; }
  double s   = isLast ? 0.0 : sig;
  double mui = isLast ? 0.0 : muv;
  double tS, tM, tY, tX;
  double inclS = dscan_incl(s, buf, i, &tS);
  dscan_incl(mui, buf, i, &tM);
  double sigLast = lastd[0], muLast = lastd[1];
  double denom = tS + sigLast;
  double c = -muLast / sigLast;
  double pre = inclS - s;
  double suffix  = denom - pre;
  double suffix1 = suffix - s;
  double sigL = isLast ? 0.0 : sqrt(s * suffix1 / suffix);
  double cL   = isLast ? 0.0 : (-s / (suffix * sigL));
  double zv   = isLast ? 0.0 : (double)zbuf[g * 255 + i];
  double y = cL * zv;
  double inclY = dscan_incl(y, buf, i, &tY);
  double Pz = inclY - y;
  double rm = s * c + mui - s * (c * tS + tM) / denom;
  double X = rm + s * Pz + sigL * zv;
  if (isLast) X = 0.0;
  dscan_incl(X, buf, i, &tX);
  out[n] = (float)(isLast ? (0.0 - tX) : X);
}

// ---------------------------------------------------------------------------
extern "C" void kernel_launch(void* const* d_in, const int* in_sizes, int n_in,
                              void* d_out, int out_size, void* d_ws, size_t ws_size,
                              hipStream_t stream) {
  const float* x      = (const float*)d_in[0];
  const float* lin0_w = (const float*)d_in[1];
  const float* ggc_w  = (const float*)d_in[2];
  const float* w_ih   = (const float*)d_in[3];
  const float* w_hh   = (const float*)d_in[4];
  const float* b_ih   = (const float*)d_in[5];
  const float* b_hh   = (const float*)d_in[6];
  const float* lin1_w = (const float*)d_in[7];
  const float* lin1_b = (const float*)d_in[8];
  const float* lin2_w = (const float*)d_in[9];
  const float* lin2_b = (const float*)d_in[10];
  const int*   ei     = (const int*)d_in[11];
  float* out = (float*)d_out;

  char* ws = (char*)d_ws;
  float*    hf     = (float*)   (ws + 0);          // 16 MB (f32 master h)
  _Float16* h16    = (_Float16*)(ws + 16777216);   // 8 MB (f16 gather shadow)
  float*    mg     = (float*)   (ws + 25165824);   // 16 MB (f32 hagg)
  ushort_t* WcH    = (ushort_t*)(ws + 41943040);   // 384 KB (4 layers)
  ushort_t* WcL    = (ushort_t*)(ws + 42336256);   // 384 KB
  ushort_t* whhH   = (ushort_t*)(ws + 42729472);   // 96 KB
  ushort_t* whhL   = (ushort_t*)(ws + 42827776);   // 96 KB
  float*    zbuf   = (float*)   (ws + 42926080);   // 128 KB [counts aliases]
  float*    mu     = (float*)   (ws + 43057152);   // 128 KB
  float*    sigma  = (float*)   (ws + 43188224);   // 128 KB
  int*      row_ptr= (int*)     (ws + 43319296);   // 128.5 KB slot
  int*      srcs   = (int*)     (ws + 43450880);   // 2 MB -> ends 45548032
  int*      counts = (int*)zbuf;                   // alias: CSR before k_zgen
  const size_t WS_NEEDED = 45548032;               // < proven 53477888
  if (ws_size < WS_NEEDED) return;

  // CSR build (counts aliases zbuf; done before k_zgen)
  k_zero<<<32, 256, 0, stream>>>(counts, N_NODES);
  k_hist<<<1024, 256, 0, stream>>>(ei, counts);
  k_scan<<<1, 1024, 0, stream>>>(counts, row_ptr);
  k_zero<<<32, 256, 0, stream>>>(counts, N_NODES);
  k_fill<<<1024, 256, 0, stream>>>(ei, row_ptr, counts, srcs);

  k_wprep<<<192, 256, 0, stream>>>(w_hh, whhH, whhL);
  k_combine<<<768, 256, 0, stream>>>(ggc_w, w_ih, WcH, WcL);
  k_zgen<<<128, 256, 0, stream>>>(zbuf);
  k_lin0<<<8192, 256, 0, stream>>>(x, lin0_w, hf, h16);

  for (int L = 0; L < 4; ++L) {
    k_agg<<<8192, 256, 0, stream>>>(h16, mg, row_ptr, srcs);
    k_gru_mfma<<<512, 256, 0, stream>>>(mg, hf, h16,
                                        WcH + (size_t)L * 49152,
                                        WcL + (size_t)L * 49152,
                                        whhH, whhL, b_ih, b_hh);
  }

  k_musig<<<8192, 256, 0, stream>>>(hf, lin1_w, lin1_b, lin2_w, lin2_b, mu, sigma);
  k_sample<<<128, 256, 0, stream>>>(mu, sigma, zbuf, out);
}